// Round 11
// baseline (1403.868 us; speedup 1.0000x reference)
//
#include <hip/hip_runtime.h>
#include <cstdint>
#include <cstddef>

typedef __bf16 bf16;
typedef __bf16 bf16x8 __attribute__((ext_vector_type(8)));
typedef __bf16 bf16x4 __attribute__((ext_vector_type(4)));
typedef float floatx4 __attribute__((ext_vector_type(4)));
typedef int   intx4  __attribute__((ext_vector_type(4)));
typedef short shortx4 __attribute__((ext_vector_type(4)));
typedef char  cx8    __attribute__((ext_vector_type(8)));

#define GLD16(gp, lp) __builtin_amdgcn_global_load_lds( \
    (const __attribute__((address_space(1))) void*)(gp), \
    (__attribute__((address_space(3))) void*)(lp), 16, 0, 0)

#define FXS 16777216.0f             // 2^24 fixed-point scale for i64 accum
#define FXI 5.9604644775390625e-08  // 2^-24

// ---------------------------------------------------------------------------
// Symmetric augment GEMM, i8 path: 128x128 upper-tri pair of C = R * R^T.
// ---------------------------------------------------------------------------
__global__ __launch_bounds__(256) void gemm_sym_i8(
    const char* __restrict__ R, short* __restrict__ Cs16, int* __restrict__ Cs32,
    int n /*lda = K*/, int kIters, int G, int pairs)
{
  __shared__ __align__(16) char As[128 * 64];
  __shared__ __align__(16) char Bs[128 * 64];

  const int pair = blockIdx.x;
  int rem = pair, bm = 0;
  while (rem >= G - bm) { rem -= G - bm; ++bm; }
  const int bn = bm + rem;
  const int m0 = bm * 128;
  const int n0 = bn * 128;

  const int t = threadIdx.x;
  const int w = t >> 6, l = t & 63;
  const int wr = w >> 1, wc = w & 1;
  const int lr = l & 15, q = l >> 4;
  const int k0base = blockIdx.y * kIters * 64;

  const char* Ab = R + (size_t)m0 * n + k0base;
  const char* Bb = R + (size_t)n0 * n + k0base;
  const int srow = t >> 2;
  const int schunk = (t & 3) * 16;

  intx4 acc[4][4];
#pragma unroll
  for (int i = 0; i < 4; ++i)
#pragma unroll
    for (int j = 0; j < 4; ++j) acc[i][j] = (intx4)0;

  for (int kb = 0; kb < kIters; ++kb) {
    const int k0 = kb * 64;
    __syncthreads();
    GLD16(Ab + (size_t)srow * n + k0 + schunk,        As + (size_t)t * 16);
    GLD16(Ab + (size_t)(srow + 64) * n + k0 + schunk, As + (size_t)(t + 256) * 16);
    GLD16(Bb + (size_t)srow * n + k0 + schunk,        Bs + (size_t)t * 16);
    GLD16(Bb + (size_t)(srow + 64) * n + k0 + schunk, Bs + (size_t)(t + 256) * 16);
    __syncthreads();

    intx4 af[4], bfr[4];
#pragma unroll
    for (int mi = 0; mi < 4; ++mi)
      af[mi] = *(const intx4*)&As[(wr * 64 + mi * 16 + lr) * 64 + q * 16];
#pragma unroll
    for (int ni = 0; ni < 4; ++ni)
      bfr[ni] = *(const intx4*)&Bs[(wc * 64 + ni * 16 + lr) * 64 + q * 16];
#pragma unroll
    for (int mi = 0; mi < 4; ++mi)
#pragma unroll
      for (int ni = 0; ni < 4; ++ni)
        acc[mi][ni] = __builtin_amdgcn_mfma_i32_16x16x64_i8(
            af[mi], bfr[ni], acc[mi][ni], 0, 0, 0);
  }

  const size_t so = ((size_t)blockIdx.y * pairs + pair) * 16384;
#pragma unroll
  for (int mi = 0; mi < 4; ++mi)
#pragma unroll
    for (int ni = 0; ni < 4; ++ni) {
      const int cl = wc * 64 + ni * 16 + lr;
      const int rb = wr * 64 + mi * 16 + q * 4;
#pragma unroll
      for (int r = 0; r < 4; ++r) {
        int v = acc[mi][ni][r];
        if (Cs16) Cs16[so + (size_t)(rb + r) * 128 + cl] = (short)v;
        else      Cs32[so + (size_t)(rb + r) * 128 + cl] = v;
      }
    }
}

// Sum integer split-K slices, write A with mirror, diag=0; fused dn raw sums
// (exact ints -> float atomics are order-exact). Grid (pairs,16).
__global__ void sym_post_i(const short* __restrict__ Cs16, const int* __restrict__ Cs32,
                           bf16* __restrict__ Abf, float* __restrict__ Af,
                           float* __restrict__ dnS,
                           int k, int G, int pairs, int nz)
{
  int rem = blockIdx.x, bm = 0;
  while (rem >= G - bm) { rem -= G - bm; ++bm; }
  const int bn = bm + rem;
  const int t = threadIdx.x;
  const int i = t >> 1;
  const int jc = blockIdx.y * 8 + (t & 1) * 4;
  const int r = bm * 128 + i;
  const size_t sbase = (size_t)blockIdx.x * 16384 + (size_t)i * 128 + jc;

  int v[4] = {0, 0, 0, 0};
  for (int z = 0; z < nz; ++z) {
    const size_t off = sbase + (size_t)z * pairs * 16384;
    if (Cs16) {
      shortx4 a = *(const shortx4*)&Cs16[off];
#pragma unroll
      for (int e = 0; e < 4; ++e) v[e] += (int)a[e];
    } else {
      intx4 a = *(const intx4*)&Cs32[off];
#pragma unroll
      for (int e = 0; e < 4; ++e) v[e] += a[e];
    }
  }
  const int c0 = bn * 128 + jc;
#pragma unroll
  for (int e = 0; e < 4; ++e)
    if (c0 + e == r) v[e] = 0;

  const int rs = v[0] + v[1] + v[2] + v[3];
  atomicAdd(&dnS[r], (float)rs);

  if (Abf) {
    bf16x4 o;
#pragma unroll
    for (int e = 0; e < 4; ++e) o[e] = (bf16)(float)v[e];
    *(bf16x4*)&Abf[(size_t)r * k + c0] = o;
    if (bm != bn) {
#pragma unroll
      for (int e = 0; e < 4; ++e) {
        Abf[(size_t)(c0 + e) * k + r] = o[e];
        atomicAdd(&dnS[c0 + e], (float)v[e]);
      }
    }
  } else {
    floatx4 o;
#pragma unroll
    for (int e = 0; e < 4; ++e) o[e] = (float)v[e];
    *(floatx4*)&Af[(size_t)r * k + c0] = o;
    if (bm != bn) {
#pragma unroll
      for (int e = 0; e < 4; ++e) {
        Af[(size_t)(c0 + e) * k + r] = o[e];
        atomicAdd(&dnS[c0 + e], (float)v[e]);
      }
    }
  }
}

// ---------------------------------------------------------------------------
// bf16 GEMM path (pool2 only: fp32-valued A2).
// ---------------------------------------------------------------------------
__global__ __launch_bounds__(256) void gemm_sym(
    const bf16* __restrict__ R, float* __restrict__ CsF,
    int n /*lda = K*/, int kIters, int G, int pairs)
{
  __shared__ __align__(16) bf16 As[128 * 32];
  __shared__ __align__(16) bf16 Bs[128 * 32];

  const int pair = blockIdx.x;
  int rem = pair, bm = 0;
  while (rem >= G - bm) { rem -= G - bm; ++bm; }
  const int bn = bm + rem;
  const int m0 = bm * 128;
  const int n0 = bn * 128;

  const int t = threadIdx.x;
  const int w = t >> 6, l = t & 63;
  const int wr = w >> 1, wc = w & 1;
  const int lr = l & 15, q = l >> 4;
  const int k0base = blockIdx.y * kIters * 32;

  const bf16* Ab = R + (size_t)m0 * n + k0base;
  const bf16* Bb = R + (size_t)n0 * n + k0base;
  const int srow = t >> 2;
  const int schunk = (t & 3) * 8;

  floatx4 acc[4][4];
#pragma unroll
  for (int i = 0; i < 4; ++i)
#pragma unroll
    for (int j = 0; j < 4; ++j) acc[i][j] = (floatx4)0.0f;

  for (int kb = 0; kb < kIters; ++kb) {
    const int k0 = kb * 32;
    __syncthreads();
    GLD16(Ab + (size_t)srow * n + k0 + schunk,        As + (size_t)t * 8);
    GLD16(Ab + (size_t)(srow + 64) * n + k0 + schunk, As + (size_t)(t + 256) * 8);
    GLD16(Bb + (size_t)srow * n + k0 + schunk,        Bs + (size_t)t * 8);
    GLD16(Bb + (size_t)(srow + 64) * n + k0 + schunk, Bs + (size_t)(t + 256) * 8);
    __syncthreads();

    bf16x8 af[4], bfr[4];
#pragma unroll
    for (int mi = 0; mi < 4; ++mi)
      af[mi] = *(const bf16x8*)&As[(wr * 64 + mi * 16 + lr) * 32 + q * 8];
#pragma unroll
    for (int ni = 0; ni < 4; ++ni)
      bfr[ni] = *(const bf16x8*)&Bs[(wc * 64 + ni * 16 + lr) * 32 + q * 8];
#pragma unroll
    for (int mi = 0; mi < 4; ++mi)
#pragma unroll
      for (int ni = 0; ni < 4; ++ni)
        acc[mi][ni] = __builtin_amdgcn_mfma_f32_16x16x32_bf16(
            af[mi], bfr[ni], acc[mi][ni], 0, 0, 0);
  }

  const size_t so = ((size_t)blockIdx.y * pairs + pair) * 16384;
#pragma unroll
  for (int mi = 0; mi < 4; ++mi)
#pragma unroll
    for (int ni = 0; ni < 4; ++ni) {
      const int cl = wc * 64 + ni * 16 + lr;
      const int rb = wr * 64 + mi * 16 + q * 4;
#pragma unroll
      for (int r = 0; r < 4; ++r)
        CsF[so + (size_t)(rb + r) * 128 + cl] = acc[mi][ni][r];
    }
}

// Sum fp split-K slices, write A (fp32) with mirror, diag=0; fused dn sums
// (A3 entries are exact ints -> order-exact float atomics). Grid (pairs,16).
__global__ void sym_post(const float* __restrict__ CsF, float* __restrict__ Af,
                         float* __restrict__ dnS,
                         int k, int G, int pairs, int nz)
{
  int rem = blockIdx.x, bm = 0;
  while (rem >= G - bm) { rem -= G - bm; ++bm; }
  const int bn = bm + rem;
  const int t = threadIdx.x;
  const int i = t >> 1;
  const int jc = blockIdx.y * 8 + (t & 1) * 4;
  const int r = bm * 128 + i;
  const size_t sbase = (size_t)blockIdx.x * 16384 + (size_t)i * 128 + jc;

  float v[4] = {0.f, 0.f, 0.f, 0.f};
  for (int z = 0; z < nz; ++z) {
    const size_t off = sbase + (size_t)z * pairs * 16384;
    floatx4 a = *(const floatx4*)&CsF[off];
#pragma unroll
    for (int e = 0; e < 4; ++e) v[e] += a[e];
  }
  const int c0 = bn * 128 + jc;
  floatx4 o;
#pragma unroll
  for (int e = 0; e < 4; ++e) o[e] = (c0 + e == r) ? 0.0f : v[e];
  atomicAdd(&dnS[r], o[0] + o[1] + o[2] + o[3]);
  *(floatx4*)&Af[(size_t)r * k + c0] = o;
  if (bm != bn) {
#pragma unroll
    for (int e = 0; e < 4; ++e) {
      Af[(size_t)(c0 + e) * k + r] = o[e];
      atomicAdd(&dnS[c0 + e], o[e]);
    }
  }
}

// ---------------------------------------------------------------------------
// Sparse aggregation for the {0,1} adjacency (layers 0 & 6): one wave per
// row; Yf[r] = sum_{c in nbr(r)} Z[c] (fp32, ascending, single writer).
// ---------------------------------------------------------------------------
__global__ __launch_bounds__(256) void agg_sparse(
    const unsigned short* __restrict__ nbr, const int* __restrict__ deg,
    const float* __restrict__ Z, float* __restrict__ Y)
{
  const int r = blockIdx.x * 4 + (threadIdx.x >> 6);
  const int l = threadIdx.x & 63;
  const unsigned short* rn = nbr + (size_t)r * 256;
  const int d = deg[r];
  float a0 = 0.f, a1 = 0.f;
  int i = 0;
  for (; i + 4 <= d; i += 4) {
    const int c0 = rn[i], c1 = rn[i + 1], c2 = rn[i + 2], c3 = rn[i + 3];
    float2 v0 = *(const float2*)(Z + (size_t)c0 * 128 + l * 2);
    float2 v1 = *(const float2*)(Z + (size_t)c1 * 128 + l * 2);
    float2 v2 = *(const float2*)(Z + (size_t)c2 * 128 + l * 2);
    float2 v3 = *(const float2*)(Z + (size_t)c3 * 128 + l * 2);
    a0 += v0.x; a1 += v0.y;
    a0 += v1.x; a1 += v1.y;
    a0 += v2.x; a1 += v2.y;
    a0 += v3.x; a1 += v3.y;
  }
  for (; i < d; ++i) {
    const int c = rn[i];
    float2 v = *(const float2*)(Z + (size_t)c * 128 + l * 2);
    a0 += v.x; a1 += v.y;
  }
  *(float2*)(Y + (size_t)r * 128 + l * 2) = make_float2(a0, a1);
}

// ---------------------------------------------------------------------------
// Aggregation M-halved (exact-int A in bf16, diag 0): i64 fixed-point atomic
// accumulation into YI (integer adds: order-exact, replay-deterministic).
// ---------------------------------------------------------------------------
template <int NP>
__global__ __launch_bounds__(256) void agg_bf(
    const bf16* __restrict__ A, int lda,
    const bf16* __restrict__ Zh, const bf16* __restrict__ Zm, const bf16* __restrict__ Zl,
    int ldz, long long* __restrict__ YI, int kIters)
{
  __shared__ __align__(16) bf16 As[64 * 32];
  __shared__ __align__(16) bf16 Zs[NP][128 * 32];

  const int t = threadIdx.x;
  const int w = t >> 6, l = t & 63;
  const int wr = w >> 1, wc = w & 1;
  const int lr = l & 15, q = l >> 4;
  const int m0 = blockIdx.x * 64;
  const int k0base = blockIdx.y * kIters * 32;

  const int srow = t >> 2;
  const int schunk = (t & 3) * 8;

  floatx4 acc[2][4];
#pragma unroll
  for (int i = 0; i < 2; ++i)
#pragma unroll
    for (int j = 0; j < 4; ++j) acc[i][j] = (floatx4)0.0f;

  for (int kb = 0; kb < kIters; ++kb) {
    const int k0 = k0base + kb * 32;
    __syncthreads();
    GLD16(A + (size_t)(m0 + srow) * lda + k0 + schunk, As + (size_t)t * 8);
    GLD16(Zh + (size_t)srow * ldz + k0 + schunk,        Zs[0] + (size_t)t * 8);
    GLD16(Zh + (size_t)(srow + 64) * ldz + k0 + schunk, Zs[0] + (size_t)(t + 256) * 8);
    GLD16(Zm + (size_t)srow * ldz + k0 + schunk,        Zs[1] + (size_t)t * 8);
    GLD16(Zm + (size_t)(srow + 64) * ldz + k0 + schunk, Zs[1] + (size_t)(t + 256) * 8);
    if (NP > 2) {
      GLD16(Zl + (size_t)srow * ldz + k0 + schunk,        Zs[2] + (size_t)t * 8);
      GLD16(Zl + (size_t)(srow + 64) * ldz + k0 + schunk, Zs[2] + (size_t)(t + 256) * 8);
    }
    __syncthreads();

    bf16x8 af[2], bz[NP][4];
#pragma unroll
    for (int mi = 0; mi < 2; ++mi)
      af[mi] = *(const bf16x8*)&As[(wr * 32 + mi * 16 + lr) * 32 + q * 8];
#pragma unroll
    for (int s = 0; s < NP; ++s)
#pragma unroll
      for (int ni = 0; ni < 4; ++ni)
        bz[s][ni] = *(const bf16x8*)&Zs[s][(wc * 64 + ni * 16 + lr) * 32 + q * 8];
#pragma unroll
    for (int s = 0; s < NP; ++s)
#pragma unroll
      for (int mi = 0; mi < 2; ++mi)
#pragma unroll
        for (int ni = 0; ni < 4; ++ni)
          acc[mi][ni] = __builtin_amdgcn_mfma_f32_16x16x32_bf16(
              af[mi], bz[s][ni], acc[mi][ni], 0, 0, 0);
  }

#pragma unroll
  for (int mi = 0; mi < 2; ++mi)
#pragma unroll
    for (int ni = 0; ni < 4; ++ni) {
      const int col = wc * 64 + ni * 16 + lr;
      const int rowb = m0 + wr * 32 + mi * 16 + q * 4;
#pragma unroll
      for (int r = 0; r < 4; ++r)
        atomicAdd((unsigned long long*)&YI[(size_t)(rowb + r) * 128 + col],
                  (unsigned long long)(long long)llrintf(acc[mi][ni][r] * FXS));
    }
}

// ---------------------------------------------------------------------------
// Aggregation M-halved (fp32 A, on-the-fly 2-plane split, diag zeroed);
// i64 fixed-point atomic accumulation.
// ---------------------------------------------------------------------------
template <int NP>
__global__ __launch_bounds__(256) void agg_split(
    const float* __restrict__ A, int lda,
    const bf16* __restrict__ Zh, const bf16* __restrict__ Zm, const bf16* __restrict__ Zl,
    int ldz, long long* __restrict__ YI, int kIters, int aTwo)
{
  __shared__ __align__(16) bf16 Ahs[64 * 32];
  __shared__ __align__(16) bf16 Als[64 * 32];
  __shared__ __align__(16) bf16 Zs[NP][128 * 32];

  const int t = threadIdx.x;
  const int w = t >> 6, l = t & 63;
  const int wr = w >> 1, wc = w & 1;
  const int lr = l & 15, q = l >> 4;
  const int m0 = blockIdx.x * 64;
  const int k0base = blockIdx.y * kIters * 32;

  const int arow = t >> 2;
  const int acol = (t & 3) * 8;
  const int srow = t >> 2;
  const int schunk = (t & 3) * 8;

  floatx4 acc[2][4];
#pragma unroll
  for (int i = 0; i < 2; ++i)
#pragma unroll
    for (int j = 0; j < 4; ++j) acc[i][j] = (floatx4)0.0f;

  for (int kb = 0; kb < kIters; ++kb) {
    const int k0 = k0base + kb * 32;
    const float* asrc = A + (size_t)(m0 + arow) * lda + k0 + acol;
    floatx4 av[2];
#pragma unroll
    for (int i = 0; i < 2; ++i) av[i] = *(const floatx4*)(asrc + i * 4);

    __syncthreads();
    GLD16(Zh + (size_t)srow * ldz + k0 + schunk,        Zs[0] + (size_t)t * 8);
    GLD16(Zh + (size_t)(srow + 64) * ldz + k0 + schunk, Zs[0] + (size_t)(t + 256) * 8);
    GLD16(Zm + (size_t)srow * ldz + k0 + schunk,        Zs[1] + (size_t)t * 8);
    GLD16(Zm + (size_t)(srow + 64) * ldz + k0 + schunk, Zs[1] + (size_t)(t + 256) * 8);
    if (NP > 2) {
      GLD16(Zl + (size_t)srow * ldz + k0 + schunk,        Zs[2] + (size_t)t * 8);
      GLD16(Zl + (size_t)(srow + 64) * ldz + k0 + schunk, Zs[2] + (size_t)(t + 256) * 8);
    }

    bf16x4 ah[2], alo[2];
    const int grow = m0 + arow;
#pragma unroll
    for (int i = 0; i < 8; ++i) {
      float v = av[i >> 2][i & 3];
      if (k0 + acol + i == grow) v = 0.0f;
      bf16 h = (bf16)v;
      ah[i >> 2][i & 3] = h;
      alo[i >> 2][i & 3] = (bf16)(v - (float)h);
    }
    const int sbase = arow * 32 + acol;
    *(bf16x4*)&Ahs[sbase] = ah[0]; *(bf16x4*)&Ahs[sbase + 4] = ah[1];
    if (aTwo) { *(bf16x4*)&Als[sbase] = alo[0]; *(bf16x4*)&Als[sbase + 4] = alo[1]; }
    __syncthreads();

    bf16x8 afh[2], afl[2], bz[NP][4];
#pragma unroll
    for (int mi = 0; mi < 2; ++mi)
      afh[mi] = *(const bf16x8*)&Ahs[(wr * 32 + mi * 16 + lr) * 32 + q * 8];
#pragma unroll
    for (int s = 0; s < NP; ++s)
#pragma unroll
      for (int ni = 0; ni < 4; ++ni)
        bz[s][ni] = *(const bf16x8*)&Zs[s][(wc * 64 + ni * 16 + lr) * 32 + q * 8];
#pragma unroll
    for (int s = 0; s < NP; ++s)
#pragma unroll
      for (int mi = 0; mi < 2; ++mi)
#pragma unroll
        for (int ni = 0; ni < 4; ++ni)
          acc[mi][ni] = __builtin_amdgcn_mfma_f32_16x16x32_bf16(
              afh[mi], bz[s][ni], acc[mi][ni], 0, 0, 0);
    if (aTwo) {
#pragma unroll
      for (int mi = 0; mi < 2; ++mi)
        afl[mi] = *(const bf16x8*)&Als[(wr * 32 + mi * 16 + lr) * 32 + q * 8];
      constexpr int NL = (NP > 2) ? 2 : 1;
#pragma unroll
      for (int s = 0; s < NL; ++s)
#pragma unroll
        for (int mi = 0; mi < 2; ++mi)
#pragma unroll
          for (int ni = 0; ni < 4; ++ni)
            acc[mi][ni] = __builtin_amdgcn_mfma_f32_16x16x32_bf16(
                afl[mi], bz[s][ni], acc[mi][ni], 0, 0, 0);
    }
  }

#pragma unroll
  for (int mi = 0; mi < 2; ++mi)
#pragma unroll
    for (int ni = 0; ni < 4; ++ni) {
      const int col = wc * 64 + ni * 16 + lr;
      const int rowb = m0 + wr * 32 + mi * 16 + q * 4;
#pragma unroll
      for (int r = 0; r < 4; ++r)
        atomicAdd((unsigned long long*)&YI[(size_t)(rowb + r) * 128 + col],
                  (unsigned long long)(long long)llrintf(acc[mi][ni][r] * FXS));
    }
}

// ---------------------------------------------------------------------------
// Z[nr,128] = dn ⊙ (x @ W). dnv holds RAW degree sums S; dn = 1/sqrt(S+2).
// statsP (prev-layer BN) in i64 fixed point. Dense layers (Zht!=null): also
// writes transposed bf16 planes and ZEROES the i64 agg buffer AggI.
// ---------------------------------------------------------------------------
template <int FULL>
__global__ __launch_bounds__(256) void xw_split(
    const float* __restrict__ X, const int* __restrict__ perm,
    const float* __restrict__ vals,
    const float* __restrict__ up, const int* __restrict__ inv,
    const long long* __restrict__ statsP, const float* __restrict__ gP,
    const float* __restrict__ bP, float nP,
    const bf16* __restrict__ Wh, const bf16* __restrict__ Wm, const bf16* __restrict__ Wl,
    const float* __restrict__ dnv, float* __restrict__ Z,
    bf16* __restrict__ Zht, bf16* __restrict__ Zmt, bf16* __restrict__ Zlt, int ldz,
    long long* __restrict__ AggI, long long* __restrict__ stats)
{
  __shared__ __align__(16) bf16 Xs[3][128 * 32];
  __shared__ __align__(16) bf16 Ws[3][128 * 32];
  __shared__ float scU[128], offU[128];

  const int t = threadIdx.x;
  if (blockIdx.x == 0) stats[t] = 0;

  const int w = t >> 6, l = t & 63;
  const int wr = w >> 1, wc = w & 1;
  const int lr = l & 15, q = l >> 4;
  const int r0 = blockIdx.x * 128;

  const int srow = t >> 1;
  const int soff = (t & 1) * 16;
  const int sbase = srow * 32 + soff;

  if (statsP) {
    if (t < 128) {
      float sm = (float)((double)statsP[t] * FXI);
      float sq = (float)((double)statsP[128 + t] * FXI);
      float m = sm / nP;
      float var = sq / nP - m * m;
      float sc = gP[t] / sqrtf(var + 1e-5f);
      scU[t] = sc;
      offU[t] = bP[t] - m * sc;
    }
    __syncthreads();
  }

  const int row = r0 + srow;
  int grow = row;
  float scale = 1.0f;
  if (perm) { grow = perm[row]; scale = vals[row]; }
  const float* xrow = X + (size_t)grow * 128;
  const float* uprow = nullptr;
  if (up) { int j = inv[row]; if (j >= 0) uprow = up + (size_t)j * 128; }

  floatx4 acc[4][4];
#pragma unroll
  for (int i = 0; i < 4; ++i)
#pragma unroll
    for (int j = 0; j < 4; ++j) acc[i][j] = (floatx4)0.0f;

  const bf16* wsrc[3] = {Wh, Wm, Wl};

  for (int ks = 0; ks < 4; ++ks) {
    const int k0 = ks * 32;
    float xv[16];
#pragma unroll
    for (int i = 0; i < 16; i += 4) {
      floatx4 tmp = *(const floatx4*)(xrow + k0 + soff + i);
      if (uprow) {
        floatx4 u = *(const floatx4*)(uprow + k0 + soff + i);
        if (statsP) {
#pragma unroll
          for (int j = 0; j < 4; ++j) {
            const int c = k0 + soff + i + j;
            u[j] = scU[c] * u[j] + offU[c];
          }
        }
        tmp += u;
      }
      xv[i] = tmp[0] * scale; xv[i + 1] = tmp[1] * scale;
      xv[i + 2] = tmp[2] * scale; xv[i + 3] = tmp[3] * scale;
    }
    bf16x8 wv[3][2];
#pragma unroll
    for (int s = 0; s < 3; ++s) {
      const bf16* ws = wsrc[s] + (size_t)srow * 128 + k0 + soff;
      wv[s][0] = *(const bf16x8*)ws;
      wv[s][1] = *(const bf16x8*)(ws + 8);
    }
    bf16x8 vh[2], vm[2], vl[2];
#pragma unroll
    for (int i = 0; i < 16; ++i) {
      float v = xv[i];
      bf16 h = (bf16)v; float r1 = v - (float)h;
      bf16 m = (bf16)r1; float r2 = r1 - (float)m;
      vh[i >> 3][i & 7] = h; vm[i >> 3][i & 7] = m; vl[i >> 3][i & 7] = (bf16)r2;
    }
    __syncthreads();
    *(bf16x8*)&Xs[0][sbase] = vh[0]; *(bf16x8*)&Xs[0][sbase + 8] = vh[1];
    *(bf16x8*)&Xs[1][sbase] = vm[0]; *(bf16x8*)&Xs[1][sbase + 8] = vm[1];
    *(bf16x8*)&Xs[2][sbase] = vl[0]; *(bf16x8*)&Xs[2][sbase + 8] = vl[1];
#pragma unroll
    for (int s = 0; s < 3; ++s) {
      *(bf16x8*)&Ws[s][sbase] = wv[s][0];
      *(bf16x8*)&Ws[s][sbase + 8] = wv[s][1];
    }
    __syncthreads();

    bf16x8 af[3][4], bfg[3][4];
#pragma unroll
    for (int s = 0; s < 3; ++s) {
#pragma unroll
      for (int mi = 0; mi < 4; ++mi)
        af[s][mi] = *(const bf16x8*)&Xs[s][(wr * 64 + mi * 16 + lr) * 32 + q * 8];
#pragma unroll
      for (int ni = 0; ni < 4; ++ni)
        bfg[s][ni] = *(const bf16x8*)&Ws[s][(wc * 64 + ni * 16 + lr) * 32 + q * 8];
    }
    constexpr int NT = FULL ? 6 : 3;
    constexpr int sa[6] = {0, 0, 1, 1, 0, 2};
    constexpr int sb[6] = {0, 1, 0, 1, 2, 0};
#pragma unroll
    for (int p = 0; p < NT; ++p)
#pragma unroll
      for (int mi = 0; mi < 4; ++mi)
#pragma unroll
        for (int ni = 0; ni < 4; ++ni)
          acc[mi][ni] = __builtin_amdgcn_mfma_f32_16x16x32_bf16(
              af[sa[p]][mi], bfg[sb[p]][ni], acc[mi][ni], 0, 0, 0);
  }

#pragma unroll
  for (int mi = 0; mi < 4; ++mi) {
    const int rowb = r0 + wr * 64 + mi * 16 + q * 4;
    float dnr[4];
#pragma unroll
    for (int r = 0; r < 4; ++r) dnr[r] = 1.0f / sqrtf(dnv[rowb + r] + 2.0f);
#pragma unroll
    for (int ni = 0; ni < 4; ++ni) {
      const int col = wc * 64 + ni * 16 + lr;
      bf16x4 h4, m4, l4;
#pragma unroll
      for (int r = 0; r < 4; ++r) {
        float v = dnr[r] * acc[mi][ni][r];
        Z[(size_t)(rowb + r) * 128 + col] = v;
        bf16 h = (bf16)v; float r1 = v - (float)h;
        bf16 m = (bf16)r1; float r2 = r1 - (float)m;
        h4[r] = h; m4[r] = m; l4[r] = (bf16)r2;
      }
      if (Zht) {
#pragma unroll
        for (int r = 0; r < 4; ++r)
          AggI[(size_t)(rowb + r) * 128 + col] = 0;
        *(bf16x4*)&Zht[(size_t)col * ldz + rowb] = h4;
        *(bf16x4*)&Zmt[(size_t)col * ldz + rowb] = m4;
        if (FULL) *(bf16x4*)&Zlt[(size_t)col * ldz + rowb] = l4;
      }
    }
  }
}

// ---------------------------------------------------------------------------
// Fused prep: blocks [0,4096): adj->bf16 row + ordered neighbor list + deg
// + dn RAW sums; [4096,4544) conv_w 3-way split; block 4544 pool_w inv norms.
// ---------------------------------------------------------------------------
__global__ void prep_all(const float* __restrict__ adj, bf16* __restrict__ ah,
                         float* __restrict__ dn, int n,
                         unsigned short* __restrict__ nbr, int* __restrict__ deg,
                         const float* __restrict__ W, bf16* __restrict__ Wh,
                         bf16* __restrict__ Wm, bf16* __restrict__ Wl,
                         const float* __restrict__ pw, float* __restrict__ invp) {
  const int bid = blockIdx.x;
  const int t = threadIdx.x;
  __shared__ int wsum4[4];
  __shared__ float red[128];
  if (bid < 4096) {
    const int r = bid;
    const float* arow = adj + (size_t)r * n;
    bf16* orow = ah + (size_t)r * n;
    const int base = t * 16;
    floatx4 buf[4];
#pragma unroll
    for (int i = 0; i < 4; ++i) buf[i] = *(const floatx4*)(arow + base + i * 4);
    int cnt = 0;
#pragma unroll
    for (int i = 0; i < 4; ++i) {
      bf16x4 o;
#pragma unroll
      for (int e = 0; e < 4; ++e) {
        float x = (base + i * 4 + e == r) ? 0.0f : buf[i][e];
        buf[i][e] = x;
        cnt += (x != 0.0f) ? 1 : 0;
        o[e] = (bf16)x;
      }
      *(bf16x4*)&orow[base + i * 4] = o;
    }
    const int lane = t & 63, wid = t >> 6;
    int vc = cnt;
#pragma unroll
    for (int off = 1; off < 64; off <<= 1) {
      int u = __shfl_up(vc, off, 64);
      if (lane >= off) vc += u;
    }
    if (lane == 63) wsum4[wid] = vc;
    __syncthreads();
    int add = 0;
    for (int wi = 0; wi < wid; ++wi) add += wsum4[wi];
    int o = vc + add - cnt;       // exclusive prefix (ascending-order slot)
    const int total = wsum4[0] + wsum4[1] + wsum4[2] + wsum4[3];
    unsigned short* rn = nbr + (size_t)r * 256;
#pragma unroll
    for (int i = 0; i < 4; ++i)
#pragma unroll
      for (int e = 0; e < 4; ++e)
        if (buf[i][e] != 0.0f) {
          if (o < 256) rn[o] = (unsigned short)(base + i * 4 + e);
          ++o;
        }
    if (t == 0) {
      deg[r] = total < 256 ? total : 256;
      dn[r] = (float)total;
    }
  } else if (bid < 4544) {
    int idx = (bid - 4096) * 256 + t;
    int l = idx >> 14, rem = idx & 16383, c = rem >> 7, k = rem & 127;
    float v = W[(l << 14) + (k << 7) + c];
    bf16 h = (bf16)v; float r1 = v - (float)h;
    bf16 m = (bf16)r1; float r2 = r1 - (float)m;
    Wh[idx] = h; Wm[idx] = m; Wl[idx] = (bf16)r2;
  } else {
    if (t < 128) {
      for (int l = 0; l < 3; ++l) {
        float v = pw[l * 128 + t];
        red[t] = v * v; __syncthreads();
        for (int off = 64; off; off >>= 1) {
          if (t < off) red[t] += red[t + off];
          __syncthreads();
        }
        if (t == 0) invp[l] = 1.0f / sqrtf(red[0]);
        __syncthreads();
      }
    }
  }
}

// ---------------------------------------------------------------------------
// Fused top-k select: radix k-th largest (snapshot-fixed) + deterministic
// compaction (+inverse perm) in one single-block kernel.
// ---------------------------------------------------------------------------
__device__ inline unsigned f2u(float f) {
  unsigned u = __float_as_uint(f);
  return (u & 0x80000000u) ? ~u : (u | 0x80000000u);
}
__global__ __launch_bounds__(1024) void select_kernel(
    const float* __restrict__ s, int n, int k,
    int* __restrict__ perm, float* __restrict__ vals, int* __restrict__ inv)
{
  __shared__ int hist[256];
  __shared__ unsigned sh_prefix;
  __shared__ int sh_krem;
  __shared__ float sh_thr;
  __shared__ int wsum[16];
  __shared__ int wgs[16], wes[16];
  const int t = threadIdx.x;
  const int lane = t & 63;
  const int wid = t >> 6;
  if (t == 0) { sh_prefix = 0; sh_krem = k; }

  for (int round = 0; round < 4; ++round) {
    const int shift = 24 - 8 * round;
    if (t < 256) hist[t] = 0;
    __syncthreads();
    const unsigned pref = sh_prefix;
    const int krem = sh_krem;
    for (int i = t; i < n; i += 1024) {
      unsigned u = f2u(s[i]);
      if (round == 0 || (u >> (shift + 8)) == pref)
        atomicAdd(&hist[(u >> shift) & 255], 1);
    }
    __syncthreads();
    int v = 0, own = 0;
    if (t < 256) {
      own = hist[255 - t];
      v = own;
#pragma unroll
      for (int off = 1; off < 64; off <<= 1) {
        int u = __shfl_up(v, off, 64);
        if (lane >= off) v += u;
      }
      if (lane == 63) wsum[wid] = v;
    }
    __syncthreads();
    if (t < 256) {
      int add = 0;
      for (int wi = 0; wi < wid; ++wi) add += wsum[wi];
      v += add;
      const int prev = v - own;
      if (v >= krem && prev < krem) {
        sh_prefix = (pref << 8) | (unsigned)(255 - t);
        sh_krem = krem - prev;
      }
    }
    __syncthreads();
  }
  if (t == 0) {
    unsigned u = sh_prefix;
    sh_thr = (u & 0x80000000u) ? __uint_as_float(u & 0x7fffffffu)
                               : __uint_as_float(~u);
  }
  for (int i = t; i < n; i += 1024) inv[i] = -1;
  __syncthreads();

  const float thr = sh_thr;
  const int chunk = n >> 10;
  const int beg = t * chunk;
  int g = 0, e = 0;
  for (int i = 0; i < chunk; ++i) {
    float v = s[beg + i];
    g += (v > thr); e += (v == thr);
  }
  int vg = g, ve = e;
#pragma unroll
  for (int off = 1; off < 64; off <<= 1) {
    int ug = __shfl_up(vg, off, 64);
    int ue = __shfl_up(ve, off, 64);
    if (lane >= off) { vg += ug; ve += ue; }
  }
  if (lane == 63) { wgs[wid] = vg; wes[wid] = ve; }
  __syncthreads();
  int ag = 0, ae = 0;
  for (int wi = 0; wi < wid; ++wi) { ag += wgs[wi]; ae += wes[wi]; }
  int total_gt = 0;
#pragma unroll
  for (int wi = 0; wi < 16; ++wi) total_gt += wgs[wi];
  int pg = vg + ag - g;
  int pe = ve + ae - e;
  const int need = k - total_gt;
  for (int i = 0; i < chunk; ++i) {
    float v = s[beg + i];
    if (v > thr) {
      if (pg < k) { perm[pg] = beg + i; vals[pg] = v; inv[beg + i] = pg; }
      ++pg;
    } else if (v == thr) {
      if (pe < need && total_gt + pe < k) {
        perm[total_gt + pe] = beg + i; vals[total_gt + pe] = v;
        inv[beg + i] = total_gt + pe;
      }
      ++pe;
    }
  }
}

// Gather R=(A+I)[perm] as int8, diag forced to 1; zero dn sum slot.
__global__ void gather_i8(const bf16* __restrict__ src, int lda,
                          const int* __restrict__ perm, char* __restrict__ R, int n,
                          float* __restrict__ dnz) {
  int j = blockIdx.x, t = threadIdx.x;
  int r = perm[j];
  if (t == 0) dnz[j] = 0.0f;
  const bf16* s = src + (size_t)r * lda;
  char* o = R + (size_t)j * n;
  for (int c = t * 8; c < n; c += 2048) {
    bf16x8 v = *(const bf16x8*)&s[c];
    cx8 ob;
#pragma unroll
    for (int e = 0; e < 8; ++e)
      ob[e] = (c + e == r) ? (char)1 : (char)(float)v[e];
    *(cx8*)&o[c] = ob;
  }
}

__global__ void gather_f32(const float* __restrict__ src, int lda,
                           const int* __restrict__ perm, bf16* __restrict__ R, int n,
                           float* __restrict__ dnz) {
  int j = blockIdx.x, t = threadIdx.x;
  int r = perm[j];
  if (t == 0) dnz[j] = 0.0f;
  const float* s = src + (size_t)r * lda;
  bf16* o = R + (size_t)j * n;
  for (int c4 = t * 4; c4 < n; c4 += 1024) {
    floatx4 v = *(const floatx4*)(s + c4);
    bf16x4 ob;
#pragma unroll
    for (int e = 0; e < 4; ++e)
      ob[e] = (c4 + e == r) ? (bf16)1.0f : (bf16)v[e];
    *(bf16x4*)&o[c4] = ob;
  }
}

// y = dn[r]*(agg + 2*Z) + bias; relu?; H to hout; BN stats in i64 fixed point.
// agg source: YsI (i64 fixed-point, dense) or YsF (fp32, sparse). dn holds
// RAW sums S; factor = 1/sqrt(S+2). Grid nr/4 x 128. hout may alias YsF
// (per-element read-before-write).
__global__ void gcn_post(const long long* __restrict__ YsI, const float* YsF,
                         const float* __restrict__ Zf,
                         const float* __restrict__ dn, const float* __restrict__ bias,
                         long long* __restrict__ stats, int relu,
                         float* hout) {
  int c = threadIdx.x;
  int r0 = blockIdx.x * 4;
  float b = bias[c];
  float s = 0.f, qq = 0.f;
  for (int i = 0; i < 4; ++i) {
    int r = r0 + i;
    float a = YsI ? (float)((double)YsI[(size_t)r * 128 + c] * FXI)
                  : YsF[(size_t)r * 128 + c];
    float d = 1.0f / sqrtf(dn[r] + 2.0f);
    float v = d * (a + 2.0f * Zf[(size_t)r * 128 + c]) + b;
    if (relu) v = fmaxf(v, 0.f);
    hout[(size_t)r * 128 + c] = v;
    s += v; qq += v * v;
  }
  atomicAdd((unsigned long long*)&stats[c],
            (unsigned long long)(long long)llrintf(s * FXS));
  atomicAdd((unsigned long long*)&stats[128 + c],
            (unsigned long long)(long long)llrintf(qq * FXS));
}

// BN apply (i64 fixed-point stats) + optional fused pooling score.
__global__ void bn_apply(const float* __restrict__ H, const long long* __restrict__ stats,
                         const float* __restrict__ g, const float* __restrict__ b,
                         int n, float* __restrict__ xout,
                         const float* __restrict__ pw, const float* __restrict__ invp,
                         float* __restrict__ scores) {
  int r = blockIdx.x, c = threadIdx.x;
  float sm = (float)((double)stats[c] * FXI);
  float sq = (float)((double)stats[128 + c] * FXI);
  float m = sm / n;
  float var = sq / n - m * m;
  float sc = g[c] / sqrtf(var + 1e-5f);
  float off = b[c] - m * sc;
  float v = sc * H[(size_t)r * 128 + c] + off;
  xout[(size_t)r * 128 + c] = v;
  if (pw) {
    __shared__ float red[128];
    red[c] = v * pw[c]; __syncthreads();
    for (int o = 64; o; o >>= 1) {
      if (c < o) red[c] += red[c + o];
      __syncthreads();
    }
    if (c == 0) scores[r] = tanhf(red[0] * invp[0]);
  }
}

// ---------------------------------------------------------------------------
extern "C" void kernel_launch(void* const* d_in, const int* in_sizes, int n_in,
                              void* d_out, int out_size, void* d_ws, size_t ws_size,
                              hipStream_t stream) {
  const float* x_in   = (const float*)d_in[0];
  const float* adj    = (const float*)d_in[1];
  const float* conv_w = (const float*)d_in[2];
  const float* conv_b = (const float*)d_in[3];
  const float* pool_w = (const float*)d_in[4];
  const float* bn_g   = (const float*)d_in[5];
  const float* bn_b   = (const float*)d_in[6];
  float* out = (float*)d_out;
  (void)in_sizes; (void)n_in; (void)out_size; (void)ws_size;

  char* p = (char*)d_ws;
  auto alloc = [&](size_t bytes) -> void* {
    void* r = (void*)p;
    p += (bytes + 255) & ~(size_t)255;
    return r;
  };
  bf16*  Ah0bf = (bf16*)alloc(4096ull * 4096 * 2);
  bf16*  A1bf  = (bf16*)alloc(2048ull * 2048 * 2);
  float* A2f   = (float*)alloc(1024ull * 1024 * 4);
  float* A3f   = (float*)alloc(512ull * 512 * 4);
  char*  Rbuf  = (char*)alloc(2048ull * 4096 * 2);  // i8 (pools 0/1) or bf16 (pool 2)
  void*  Cs    = alloc(40ull << 20);
  float* Z     = (float*)alloc(4096ull * 128 * 4);
  bf16*  Zht   = (bf16*)alloc(128ull * 4096 * 2);
  bf16*  Zmt   = (bf16*)alloc(128ull * 4096 * 2);
  bf16*  Zlt   = (bf16*)alloc(128ull * 4096 * 2);
  float* Agg   = (float*)alloc(4096ull * 128 * 4);      // sparse agg + H buffer
  long long* AggI = (long long*)alloc(4096ull * 128 * 8); // dense i64 agg
  float* res0  = (float*)alloc(4096ull * 128 * 4);
  float* res1  = (float*)alloc(2048ull * 128 * 4);
  float* res2  = (float*)alloc(1024ull * 128 * 4);
  float* xb0   = (float*)alloc(512ull * 128 * 4);
  float* xb1   = (float*)alloc(1024ull * 128 * 4);
  float* xb2   = (float*)alloc(2048ull * 128 * 4);
  bf16*  Wh    = (bf16*)alloc(7ull * 16384 * 2);
  bf16*  Wm    = (bf16*)alloc(7ull * 16384 * 2);
  bf16*  Wl    = (bf16*)alloc(7ull * 16384 * 2);
  unsigned short* nbr = (unsigned short*)alloc(4096ull * 256 * 2 + 1024);
  int*   deg   = (int*)alloc(4096 * 4);
  float* scores = (float*)alloc(4096 * 4);
  int*   perm0 = (int*)alloc(2048 * 4);
  int*   perm1 = (int*)alloc(1024 * 4);
  int*   perm2 = (int*)alloc(512 * 4);
  int*   inv0  = (int*)alloc(4096 * 4);
  int*   inv1  = (int*)alloc(2048 * 4);
  int*   inv2  = (int*)alloc(1024 * 4);
  float* vals0 = (float*)alloc(2048 * 4);
  float* vals1 = (float*)alloc(1024 * 4);
  float* vals2 = (float*)alloc(512 * 4);
  float* dn0   = (float*)alloc(4096 * 4);   // all dn buffers hold RAW sums S
  float* dn1   = (float*)alloc(2048 * 4);
  float* dn2   = (float*)alloc(1024 * 4);
  float* dn3   = (float*)alloc(512 * 4);
  float* invp  = (float*)alloc(256);
  long long* stats = (long long*)alloc(7ull * 256 * 8);  // per-layer i64 BN stats

  auto gcn = [&](int nr, const bf16* Abf, const float* Af32,
                 const unsigned short* nbrp, const float* dnv,
                 int layer, const float* xsrc, const int* perm, const float* vals,
                 const float* up, const int* inv, float* xout, int relu, int aTwo,
                 const float* pw, const float* ip, int full,
                 const long long* statsP, const float* gP, const float* bPv, float nP,
                 int doBn) {
    long long* st = stats + layer * 256;
    bf16* zht = nbrp ? nullptr : Zht;
    bf16* zmt = nbrp ? nullptr : Zmt;
    bf16* zlt = nbrp ? nullptr : Zlt;
    if (full)
      xw_split<1><<<nr / 128, 256, 0, stream>>>(
          xsrc, perm, vals, up, inv, statsP, gP, bPv, nP,
          Wh + layer * 16384, Wm + layer * 16384, Wl + layer * 16384, dnv,
          Z, zht, zmt, zlt, nr, AggI, st);
    else
      xw_split<0><<<nr / 128, 256, 0, stream>>>(
          xsrc, perm, vals, up, inv, statsP, gP, bPv, nP,
          Wh + layer * 16384, Wm + layer * 16384, Wl + layer * 16384, dnv,
          Z, zht, zmt, zlt, nr, AggI, st);
    const long long* aggI = nullptr;
    if (nbrp) {
      agg_sparse<<<nr / 4, 256, 0, stream>>>(nbrp, deg, Z, Agg);
    } else if (Abf) {
      if (full)
        agg_bf<3><<<dim3(nr / 64, 8), 256, 0, stream>>>(
            Abf, nr, Zht, Zmt, Zlt, nr, AggI, nr / 256);
      else
        agg_bf<2><<<dim3(nr / 64, 8), 256, 0, stream>>>(
            Abf, nr, Zht, Zmt, Zlt, nr, AggI, nr / 256);
      aggI = AggI;
    } else {
      if (full)
        agg_split<3><<<dim3(nr / 64, 8), 256, 0, stream>>>(
            Af32, nr, Zht, Zmt, Zlt, nr, AggI, nr / 256, aTwo);
      else
        agg_split<2><<<dim3(nr / 64, 8), 256, 0, stream>>>(
            Af32, nr, Zht, Zmt, Zlt, nr, AggI, nr / 256, aTwo);
      aggI = AggI;
    }
    gcn_post<<<nr / 4, 128, 0, stream>>>(aggI, Agg, Z, dnv, conv_b + layer * 128,
                                         st, relu, doBn ? Agg : xout);
    if (doBn)
      bn_apply<<<nr, 128, 0, stream>>>(Agg, st, bn_g + layer * 128, bn_b + layer * 128,
                                       nr, xout, pw, ip, scores);
  };

  auto pool = [&](int n, const bf16* srcBf, const float* srcF32,
                  bf16* outBf, float* outF32, float* dnNew,
                  int* perm, float* vals, int* inv, int splitZ, int mode) {
    int k = n / 2, G = k / 128, pairs = G * (G + 1) / 2;
    select_kernel<<<1, 1024, 0, stream>>>(scores, n, k, perm, vals, inv);
    if (mode <= 1) {
      gather_i8<<<k, 256, 0, stream>>>(srcBf, n, perm, Rbuf, n, dnNew);
      gemm_sym_i8<<<dim3(pairs, splitZ), 256, 0, stream>>>(
          Rbuf, mode == 0 ? (short*)Cs : nullptr, mode == 0 ? nullptr : (int*)Cs,
          n, n / (splitZ * 64), G, pairs);
      sym_post_i<<<dim3(pairs, 16), 256, 0, stream>>>(
          mode == 0 ? (const short*)Cs : nullptr, mode == 0 ? nullptr : (const int*)Cs,
          outBf, outF32, dnNew, k, G, pairs, splitZ);
    } else {
      gather_f32<<<k, 256, 0, stream>>>(srcF32, n, perm, (bf16*)Rbuf, n, dnNew);
      gemm_sym<<<dim3(pairs, splitZ), 256, 0, stream>>>(
          (const bf16*)Rbuf, (float*)Cs, n, n / (splitZ * 32), G, pairs);
      sym_post<<<dim3(pairs, 16), 256, 0, stream>>>(
          (const float*)Cs, outF32, dnNew, k, G, pairs, splitZ);
    }
  };

  // ---- prep (one launch; builds Ah0 bf16 + ordered adjacency + dn0 raw) ----
  prep_all<<<4545, 256, 0, stream>>>(adj, Ah0bf, dn0, 4096, nbr, deg,
                                     conv_w, Wh, Wm, Wl, pool_w, invp);

  // ---- down ----
  gcn(4096, nullptr, nullptr, nbr, dn0, 0, x_in, nullptr, nullptr, nullptr, nullptr,
      res0, 1, 0, pool_w + 0, invp + 0, 1, nullptr, nullptr, nullptr, 1.0f, 1);
  pool(4096, Ah0bf, nullptr, A1bf, nullptr, dn1, perm0, vals0, inv0, 4, 0);
  gcn(2048, A1bf, nullptr, nullptr, dn1, 1, res0, perm0, vals0, nullptr, nullptr,
      res1, 1, 0, pool_w + 128, invp + 1, 1, nullptr, nullptr, nullptr, 1.0f, 1);
  pool(2048, A1bf, nullptr, nullptr, A2f, dn2, perm1, vals1, inv1, 8, 1);
  gcn(1024, nullptr, A2f, nullptr, dn2, 2, res1, perm1, vals1, nullptr, nullptr,
      res2, 1, 1, pool_w + 256, invp + 2, 1, nullptr, nullptr, nullptr, 1.0f, 1);
  pool(1024, nullptr, A2f, nullptr, A3f, dn3, perm2, vals2, inv2, 8, 2);
  gcn(512, nullptr, A3f, nullptr, dn3, 3, res2, perm2, vals2, nullptr, nullptr,
      xb0, 1, 1, nullptr, nullptr, 0, nullptr, nullptr, nullptr, 1.0f, 0);

  // ---- up ----
  gcn(1024, nullptr, A2f, nullptr, dn2, 4, res2, nullptr, nullptr, xb0, inv2,
      xb1, 1, 1, nullptr, nullptr, 0,
      stats + 3 * 256, bn_g + 3 * 128, bn_b + 3 * 128, 512.0f, 0);
  gcn(2048, A1bf, nullptr, nullptr, dn1, 5, res1, nullptr, nullptr, xb1, inv1,
      xb2, 1, 0, nullptr, nullptr, 0,
      stats + 4 * 256, bn_g + 4 * 128, bn_b + 4 * 128, 1024.0f, 0);
  gcn(4096, nullptr, nullptr, nbr, dn0, 6, res0, nullptr, nullptr, xb2, inv0,
      out, 0, 0, nullptr, nullptr, 0,
      stats + 5 * 256, bn_g + 5 * 128, bn_b + 5 * 128, 2048.0f, 1);
}

// Round 12
// 488.459 us; speedup vs baseline: 2.8741x; 2.8741x over previous
//
#include <hip/hip_runtime.h>
#include <cstdint>
#include <cstddef>

typedef __bf16 bf16;
typedef __bf16 bf16x8 __attribute__((ext_vector_type(8)));
typedef __bf16 bf16x4 __attribute__((ext_vector_type(4)));
typedef float floatx4 __attribute__((ext_vector_type(4)));
typedef int   intx4  __attribute__((ext_vector_type(4)));
typedef short shortx4 __attribute__((ext_vector_type(4)));
typedef char  cx8    __attribute__((ext_vector_type(8)));

#define GLD16(gp, lp) __builtin_amdgcn_global_load_lds( \
    (const __attribute__((address_space(1))) void*)(gp), \
    (__attribute__((address_space(3))) void*)(lp), 16, 0, 0)

// ---------------------------------------------------------------------------
// Symmetric augment GEMM, i8 path: 128x128 upper-tri pair of C = R * R^T.
// R entries are small exact ints (pool0: {0,1}; pool1: counts <= 127).
// ---------------------------------------------------------------------------
__global__ __launch_bounds__(256) void gemm_sym_i8(
    const char* __restrict__ R, short* __restrict__ Cs16, int* __restrict__ Cs32,
    int n /*lda = K*/, int kIters, int G, int pairs)
{
  __shared__ __align__(16) char As[128 * 64];
  __shared__ __align__(16) char Bs[128 * 64];

  const int pair = blockIdx.x;
  int rem = pair, bm = 0;
  while (rem >= G - bm) { rem -= G - bm; ++bm; }
  const int bn = bm + rem;
  const int m0 = bm * 128;
  const int n0 = bn * 128;

  const int t = threadIdx.x;
  const int w = t >> 6, l = t & 63;
  const int wr = w >> 1, wc = w & 1;
  const int lr = l & 15, q = l >> 4;
  const int k0base = blockIdx.y * kIters * 64;

  const char* Ab = R + (size_t)m0 * n + k0base;
  const char* Bb = R + (size_t)n0 * n + k0base;
  const int srow = t >> 2;
  const int schunk = (t & 3) * 16;

  intx4 acc[4][4];
#pragma unroll
  for (int i = 0; i < 4; ++i)
#pragma unroll
    for (int j = 0; j < 4; ++j) acc[i][j] = (intx4)0;

  for (int kb = 0; kb < kIters; ++kb) {
    const int k0 = kb * 64;
    __syncthreads();
    GLD16(Ab + (size_t)srow * n + k0 + schunk,        As + (size_t)t * 16);
    GLD16(Ab + (size_t)(srow + 64) * n + k0 + schunk, As + (size_t)(t + 256) * 16);
    GLD16(Bb + (size_t)srow * n + k0 + schunk,        Bs + (size_t)t * 16);
    GLD16(Bb + (size_t)(srow + 64) * n + k0 + schunk, Bs + (size_t)(t + 256) * 16);
    __syncthreads();

    intx4 af[4], bfr[4];
#pragma unroll
    for (int mi = 0; mi < 4; ++mi)
      af[mi] = *(const intx4*)&As[(wr * 64 + mi * 16 + lr) * 64 + q * 16];
#pragma unroll
    for (int ni = 0; ni < 4; ++ni)
      bfr[ni] = *(const intx4*)&Bs[(wc * 64 + ni * 16 + lr) * 64 + q * 16];
#pragma unroll
    for (int mi = 0; mi < 4; ++mi)
#pragma unroll
      for (int ni = 0; ni < 4; ++ni)
        acc[mi][ni] = __builtin_amdgcn_mfma_i32_16x16x64_i8(
            af[mi], bfr[ni], acc[mi][ni], 0, 0, 0);
  }

  const size_t so = ((size_t)blockIdx.y * pairs + pair) * 16384;
#pragma unroll
  for (int mi = 0; mi < 4; ++mi)
#pragma unroll
    for (int ni = 0; ni < 4; ++ni) {
      const int cl = wc * 64 + ni * 16 + lr;
      const int rb = wr * 64 + mi * 16 + q * 4;
#pragma unroll
      for (int r = 0; r < 4; ++r) {
        int v = acc[mi][ni][r];
        if (Cs16) Cs16[so + (size_t)(rb + r) * 128 + cl] = (short)v;
        else      Cs32[so + (size_t)(rb + r) * 128 + cl] = v;
      }
    }
}

// Sum integer split-K slices, write A with mirror, diag=0. Grid (pairs,16).
__global__ void sym_post_i(const short* __restrict__ Cs16, const int* __restrict__ Cs32,
                           bf16* __restrict__ Abf, float* __restrict__ Af,
                           int k, int G, int pairs, int nz)
{
  int rem = blockIdx.x, bm = 0;
  while (rem >= G - bm) { rem -= G - bm; ++bm; }
  const int bn = bm + rem;
  const int t = threadIdx.x;
  const int i = t >> 1;
  const int jc = blockIdx.y * 8 + (t & 1) * 4;
  const int r = bm * 128 + i;
  const size_t sbase = (size_t)blockIdx.x * 16384 + (size_t)i * 128 + jc;

  int v[4] = {0, 0, 0, 0};
  for (int z = 0; z < nz; ++z) {
    const size_t off = sbase + (size_t)z * pairs * 16384;
    if (Cs16) {
      shortx4 a = *(const shortx4*)&Cs16[off];
#pragma unroll
      for (int e = 0; e < 4; ++e) v[e] += (int)a[e];
    } else {
      intx4 a = *(const intx4*)&Cs32[off];
#pragma unroll
      for (int e = 0; e < 4; ++e) v[e] += a[e];
    }
  }
  const int c0 = bn * 128 + jc;
#pragma unroll
  for (int e = 0; e < 4; ++e)
    if (c0 + e == r) v[e] = 0;

  if (Abf) {
    bf16x4 o;
#pragma unroll
    for (int e = 0; e < 4; ++e) o[e] = (bf16)(float)v[e];
    *(bf16x4*)&Abf[(size_t)r * k + c0] = o;
    if (bm != bn) {
#pragma unroll
      for (int e = 0; e < 4; ++e)
        Abf[(size_t)(c0 + e) * k + r] = o[e];
    }
  } else {
    floatx4 o;
#pragma unroll
    for (int e = 0; e < 4; ++e) o[e] = (float)v[e];
    *(floatx4*)&Af[(size_t)r * k + c0] = o;
    if (bm != bn) {
#pragma unroll
      for (int e = 0; e < 4; ++e)
        Af[(size_t)(c0 + e) * k + r] = o[e];
    }
  }
}

// ---------------------------------------------------------------------------
// bf16 GEMM path (pool2 only: fp32-valued A2).
// ---------------------------------------------------------------------------
__global__ __launch_bounds__(256) void gemm_sym(
    const bf16* __restrict__ R, float* __restrict__ CsF,
    int n /*lda = K*/, int kIters, int G, int pairs)
{
  __shared__ __align__(16) bf16 As[128 * 32];
  __shared__ __align__(16) bf16 Bs[128 * 32];

  const int pair = blockIdx.x;
  int rem = pair, bm = 0;
  while (rem >= G - bm) { rem -= G - bm; ++bm; }
  const int bn = bm + rem;
  const int m0 = bm * 128;
  const int n0 = bn * 128;

  const int t = threadIdx.x;
  const int w = t >> 6, l = t & 63;
  const int wr = w >> 1, wc = w & 1;
  const int lr = l & 15, q = l >> 4;
  const int k0base = blockIdx.y * kIters * 32;

  const bf16* Ab = R + (size_t)m0 * n + k0base;
  const bf16* Bb = R + (size_t)n0 * n + k0base;
  const int srow = t >> 2;
  const int schunk = (t & 3) * 8;

  floatx4 acc[4][4];
#pragma unroll
  for (int i = 0; i < 4; ++i)
#pragma unroll
    for (int j = 0; j < 4; ++j) acc[i][j] = (floatx4)0.0f;

  for (int kb = 0; kb < kIters; ++kb) {
    const int k0 = kb * 32;
    __syncthreads();
    GLD16(Ab + (size_t)srow * n + k0 + schunk,        As + (size_t)t * 8);
    GLD16(Ab + (size_t)(srow + 64) * n + k0 + schunk, As + (size_t)(t + 256) * 8);
    GLD16(Bb + (size_t)srow * n + k0 + schunk,        Bs + (size_t)t * 8);
    GLD16(Bb + (size_t)(srow + 64) * n + k0 + schunk, Bs + (size_t)(t + 256) * 8);
    __syncthreads();

    bf16x8 af[4], bfr[4];
#pragma unroll
    for (int mi = 0; mi < 4; ++mi)
      af[mi] = *(const bf16x8*)&As[(wr * 64 + mi * 16 + lr) * 32 + q * 8];
#pragma unroll
    for (int ni = 0; ni < 4; ++ni)
      bfr[ni] = *(const bf16x8*)&Bs[(wc * 64 + ni * 16 + lr) * 32 + q * 8];
#pragma unroll
    for (int mi = 0; mi < 4; ++mi)
#pragma unroll
      for (int ni = 0; ni < 4; ++ni)
        acc[mi][ni] = __builtin_amdgcn_mfma_f32_16x16x32_bf16(
            af[mi], bfr[ni], acc[mi][ni], 0, 0, 0);
  }

  const size_t so = ((size_t)blockIdx.y * pairs + pair) * 16384;
#pragma unroll
  for (int mi = 0; mi < 4; ++mi)
#pragma unroll
    for (int ni = 0; ni < 4; ++ni) {
      const int cl = wc * 64 + ni * 16 + lr;
      const int rb = wr * 64 + mi * 16 + q * 4;
#pragma unroll
      for (int r = 0; r < 4; ++r)
        CsF[so + (size_t)(rb + r) * 128 + cl] = acc[mi][ni][r];
    }
}

// Sum fp split-K slices, write A (fp32) with mirror, diag=0. Grid (pairs,16).
__global__ void sym_post(const float* __restrict__ CsF, float* __restrict__ Af,
                         int k, int G, int pairs, int nz)
{
  int rem = blockIdx.x, bm = 0;
  while (rem >= G - bm) { rem -= G - bm; ++bm; }
  const int bn = bm + rem;
  const int t = threadIdx.x;
  const int i = t >> 1;
  const int jc = blockIdx.y * 8 + (t & 1) * 4;
  const int r = bm * 128 + i;
  const size_t sbase = (size_t)blockIdx.x * 16384 + (size_t)i * 128 + jc;

  float v[4] = {0.f, 0.f, 0.f, 0.f};
  for (int z = 0; z < nz; ++z) {
    const size_t off = sbase + (size_t)z * pairs * 16384;
    floatx4 a = *(const floatx4*)&CsF[off];
#pragma unroll
    for (int e = 0; e < 4; ++e) v[e] += a[e];
  }
  const int c0 = bn * 128 + jc;
  floatx4 o;
#pragma unroll
  for (int e = 0; e < 4; ++e) o[e] = (c0 + e == r) ? 0.0f : v[e];
  *(floatx4*)&Af[(size_t)r * k + c0] = o;
  if (bm != bn) {
#pragma unroll
    for (int e = 0; e < 4; ++e)
      Af[(size_t)(c0 + e) * k + r] = o[e];
  }
}

// ---------------------------------------------------------------------------
// Sparse aggregation (layer 6 only: post-selection, output path). One wave
// per row; Y[r] = sum_{c in nbr(r)} Z[c] (fp32, ascending, single writer —
// deterministic). Z is 2MB -> L2-resident.
// ---------------------------------------------------------------------------
__global__ __launch_bounds__(256) void agg_sparse(
    const unsigned short* __restrict__ nbr, const int* __restrict__ deg,
    const float* __restrict__ Z, float* __restrict__ Y)
{
  const int r = blockIdx.x * 4 + (threadIdx.x >> 6);
  const int l = threadIdx.x & 63;
  const unsigned short* rn = nbr + (size_t)r * 256;
  const int d = deg[r];
  float a0 = 0.f, a1 = 0.f;
  int i = 0;
  for (; i + 4 <= d; i += 4) {
    const int c0 = rn[i], c1 = rn[i + 1], c2 = rn[i + 2], c3 = rn[i + 3];
    float2 v0 = *(const float2*)(Z + (size_t)c0 * 128 + l * 2);
    float2 v1 = *(const float2*)(Z + (size_t)c1 * 128 + l * 2);
    float2 v2 = *(const float2*)(Z + (size_t)c2 * 128 + l * 2);
    float2 v3 = *(const float2*)(Z + (size_t)c3 * 128 + l * 2);
    a0 += v0.x; a1 += v0.y;
    a0 += v1.x; a1 += v1.y;
    a0 += v2.x; a1 += v2.y;
    a0 += v3.x; a1 += v3.y;
  }
  for (; i < d; ++i) {
    const int c = rn[i];
    float2 v = *(const float2*)(Z + (size_t)c * 128 + l * 2);
    a0 += v.x; a1 += v.y;
  }
  *(float2*)(Y + (size_t)r * 128 + l * 2) = make_float2(a0, a1);
}

// ---------------------------------------------------------------------------
// Aggregation M-halved (exact-int A in bf16, diag 0): Y += A @ Z (NP planes).
// ---------------------------------------------------------------------------
template <int NP>
__global__ __launch_bounds__(256) void agg_bf(
    const bf16* __restrict__ A, int lda,
    const bf16* __restrict__ Zh, const bf16* __restrict__ Zm, const bf16* __restrict__ Zl,
    int ldz, float* __restrict__ Y, int kIters)
{
  __shared__ __align__(16) bf16 As[64 * 32];
  __shared__ __align__(16) bf16 Zs[NP][128 * 32];

  const int t = threadIdx.x;
  const int w = t >> 6, l = t & 63;
  const int wr = w >> 1, wc = w & 1;
  const int lr = l & 15, q = l >> 4;
  const int m0 = blockIdx.x * 64;
  const int k0base = blockIdx.y * kIters * 32;

  const int srow = t >> 2;
  const int schunk = (t & 3) * 8;

  floatx4 acc[2][4];
#pragma unroll
  for (int i = 0; i < 2; ++i)
#pragma unroll
    for (int j = 0; j < 4; ++j) acc[i][j] = (floatx4)0.0f;

  for (int kb = 0; kb < kIters; ++kb) {
    const int k0 = k0base + kb * 32;
    __syncthreads();
    GLD16(A + (size_t)(m0 + srow) * lda + k0 + schunk, As + (size_t)t * 8);
    GLD16(Zh + (size_t)srow * ldz + k0 + schunk,        Zs[0] + (size_t)t * 8);
    GLD16(Zh + (size_t)(srow + 64) * ldz + k0 + schunk, Zs[0] + (size_t)(t + 256) * 8);
    GLD16(Zm + (size_t)srow * ldz + k0 + schunk,        Zs[1] + (size_t)t * 8);
    GLD16(Zm + (size_t)(srow + 64) * ldz + k0 + schunk, Zs[1] + (size_t)(t + 256) * 8);
    if (NP > 2) {
      GLD16(Zl + (size_t)srow * ldz + k0 + schunk,        Zs[2] + (size_t)t * 8);
      GLD16(Zl + (size_t)(srow + 64) * ldz + k0 + schunk, Zs[2] + (size_t)(t + 256) * 8);
    }
    __syncthreads();

    bf16x8 af[2], bz[NP][4];
#pragma unroll
    for (int mi = 0; mi < 2; ++mi)
      af[mi] = *(const bf16x8*)&As[(wr * 32 + mi * 16 + lr) * 32 + q * 8];
#pragma unroll
    for (int s = 0; s < NP; ++s)
#pragma unroll
      for (int ni = 0; ni < 4; ++ni)
        bz[s][ni] = *(const bf16x8*)&Zs[s][(wc * 64 + ni * 16 + lr) * 32 + q * 8];
#pragma unroll
    for (int s = 0; s < NP; ++s)
#pragma unroll
      for (int mi = 0; mi < 2; ++mi)
#pragma unroll
        for (int ni = 0; ni < 4; ++ni)
          acc[mi][ni] = __builtin_amdgcn_mfma_f32_16x16x32_bf16(
              af[mi], bz[s][ni], acc[mi][ni], 0, 0, 0);
  }

#pragma unroll
  for (int mi = 0; mi < 2; ++mi)
#pragma unroll
    for (int ni = 0; ni < 4; ++ni) {
      const int col = wc * 64 + ni * 16 + lr;
      const int rowb = m0 + wr * 32 + mi * 16 + q * 4;
#pragma unroll
      for (int r = 0; r < 4; ++r)
        atomicAdd(&Y[(size_t)(rowb + r) * 128 + col], acc[mi][ni][r]);
    }
}

// ---------------------------------------------------------------------------
// Aggregation M-halved (fp32 A, on-the-fly 2-plane split, diag zeroed).
// ---------------------------------------------------------------------------
template <int NP>
__global__ __launch_bounds__(256) void agg_split(
    const float* __restrict__ A, int lda,
    const bf16* __restrict__ Zh, const bf16* __restrict__ Zm, const bf16* __restrict__ Zl,
    int ldz, float* __restrict__ Y, int kIters, int aTwo)
{
  __shared__ __align__(16) bf16 Ahs[64 * 32];
  __shared__ __align__(16) bf16 Als[64 * 32];
  __shared__ __align__(16) bf16 Zs[NP][128 * 32];

  const int t = threadIdx.x;
  const int w = t >> 6, l = t & 63;
  const int wr = w >> 1, wc = w & 1;
  const int lr = l & 15, q = l >> 4;
  const int m0 = blockIdx.x * 64;
  const int k0base = blockIdx.y * kIters * 32;

  const int arow = t >> 2;
  const int acol = (t & 3) * 8;
  const int srow = t >> 2;
  const int schunk = (t & 3) * 8;

  floatx4 acc[2][4];
#pragma unroll
  for (int i = 0; i < 2; ++i)
#pragma unroll
    for (int j = 0; j < 4; ++j) acc[i][j] = (floatx4)0.0f;

  for (int kb = 0; kb < kIters; ++kb) {
    const int k0 = k0base + kb * 32;
    const float* asrc = A + (size_t)(m0 + arow) * lda + k0 + acol;
    floatx4 av[2];
#pragma unroll
    for (int i = 0; i < 2; ++i) av[i] = *(const floatx4*)(asrc + i * 4);

    __syncthreads();
    GLD16(Zh + (size_t)srow * ldz + k0 + schunk,        Zs[0] + (size_t)t * 8);
    GLD16(Zh + (size_t)(srow + 64) * ldz + k0 + schunk, Zs[0] + (size_t)(t + 256) * 8);
    GLD16(Zm + (size_t)srow * ldz + k0 + schunk,        Zs[1] + (size_t)t * 8);
    GLD16(Zm + (size_t)(srow + 64) * ldz + k0 + schunk, Zs[1] + (size_t)(t + 256) * 8);
    if (NP > 2) {
      GLD16(Zl + (size_t)srow * ldz + k0 + schunk,        Zs[2] + (size_t)t * 8);
      GLD16(Zl + (size_t)(srow + 64) * ldz + k0 + schunk, Zs[2] + (size_t)(t + 256) * 8);
    }

    bf16x4 ah[2], alo[2];
    const int grow = m0 + arow;
#pragma unroll
    for (int i = 0; i < 8; ++i) {
      float v = av[i >> 2][i & 3];
      if (k0 + acol + i == grow) v = 0.0f;
      bf16 h = (bf16)v;
      ah[i >> 2][i & 3] = h;
      alo[i >> 2][i & 3] = (bf16)(v - (float)h);
    }
    const int sbase = arow * 32 + acol;
    *(bf16x4*)&Ahs[sbase] = ah[0]; *(bf16x4*)&Ahs[sbase + 4] = ah[1];
    if (aTwo) { *(bf16x4*)&Als[sbase] = alo[0]; *(bf16x4*)&Als[sbase + 4] = alo[1]; }
    __syncthreads();

    bf16x8 afh[2], afl[2], bz[NP][4];
#pragma unroll
    for (int mi = 0; mi < 2; ++mi)
      afh[mi] = *(const bf16x8*)&Ahs[(wr * 32 + mi * 16 + lr) * 32 + q * 8];
#pragma unroll
    for (int s = 0; s < NP; ++s)
#pragma unroll
      for (int ni = 0; ni < 4; ++ni)
        bz[s][ni] = *(const bf16x8*)&Zs[s][(wc * 64 + ni * 16 + lr) * 32 + q * 8];
#pragma unroll
    for (int s = 0; s < NP; ++s)
#pragma unroll
      for (int mi = 0; mi < 2; ++mi)
#pragma unroll
        for (int ni = 0; ni < 4; ++ni)
          acc[mi][ni] = __builtin_amdgcn_mfma_f32_16x16x32_bf16(
              afh[mi], bz[s][ni], acc[mi][ni], 0, 0, 0);
    if (aTwo) {
#pragma unroll
      for (int mi = 0; mi < 2; ++mi)
        afl[mi] = *(const bf16x8*)&Als[(wr * 32 + mi * 16 + lr) * 32 + q * 8];
      constexpr int NL = (NP > 2) ? 2 : 1;
#pragma unroll
      for (int s = 0; s < NL; ++s)
#pragma unroll
        for (int mi = 0; mi < 2; ++mi)
#pragma unroll
          for (int ni = 0; ni < 4; ++ni)
            acc[mi][ni] = __builtin_amdgcn_mfma_f32_16x16x32_bf16(
                afl[mi], bz[s][ni], acc[mi][ni], 0, 0, 0);
    }
  }

#pragma unroll
  for (int mi = 0; mi < 2; ++mi)
#pragma unroll
    for (int ni = 0; ni < 4; ++ni) {
      const int col = wc * 64 + ni * 16 + lr;
      const int rowb = m0 + wr * 32 + mi * 16 + q * 4;
#pragma unroll
      for (int r = 0; r < 4; ++r)
        atomicAdd(&Y[(size_t)(rowb + r) * 128 + col], acc[mi][ni][r]);
    }
}

// ---------------------------------------------------------------------------
// Z[nr,128] = dn ⊙ (x @ W); pool / unpool fusion; prev-layer BN fold.
// Transposed bf16 planes written only when Zht != nullptr.
// ---------------------------------------------------------------------------
template <int FULL>
__global__ __launch_bounds__(256) void xw_split(
    const float* __restrict__ X, const int* __restrict__ perm,
    const float* __restrict__ vals,
    const float* __restrict__ up, const int* __restrict__ inv,
    const float* __restrict__ statsP, const float* __restrict__ gP,
    const float* __restrict__ bP, float nP,
    const bf16* __restrict__ Wh, const bf16* __restrict__ Wm, const bf16* __restrict__ Wl,
    const float* __restrict__ dnv, float* __restrict__ Z,
    bf16* __restrict__ Zht, bf16* __restrict__ Zmt, bf16* __restrict__ Zlt, int ldz,
    float* __restrict__ Agg, float* __restrict__ stats)
{
  __shared__ __align__(16) bf16 Xs[3][128 * 32];
  __shared__ __align__(16) bf16 Ws[3][128 * 32];
  __shared__ float scU[128], offU[128];

  const int t = threadIdx.x;
  if (blockIdx.x == 0) stats[t] = 0.0f;

  const int w = t >> 6, l = t & 63;
  const int wr = w >> 1, wc = w & 1;
  const int lr = l & 15, q = l >> 4;
  const int r0 = blockIdx.x * 128;

  const int srow = t >> 1;
  const int soff = (t & 1) * 16;
  const int sbase = srow * 32 + soff;

  if (statsP) {
    if (t < 128) {
      float m = statsP[t] / nP;
      float var = statsP[128 + t] / nP - m * m;
      float sc = gP[t] / sqrtf(var + 1e-5f);
      scU[t] = sc;
      offU[t] = bP[t] - m * sc;
    }
    __syncthreads();
  }

  const int row = r0 + srow;
  int grow = row;
  float scale = 1.0f;
  if (perm) { grow = perm[row]; scale = vals[row]; }
  const float* xrow = X + (size_t)grow * 128;
  const float* uprow = nullptr;
  if (up) { int j = inv[row]; if (j >= 0) uprow = up + (size_t)j * 128; }

  floatx4 acc[4][4];
#pragma unroll
  for (int i = 0; i < 4; ++i)
#pragma unroll
    for (int j = 0; j < 4; ++j) acc[i][j] = (floatx4)0.0f;

  const bf16* wsrc[3] = {Wh, Wm, Wl};

  for (int ks = 0; ks < 4; ++ks) {
    const int k0 = ks * 32;
    float xv[16];
#pragma unroll
    for (int i = 0; i < 16; i += 4) {
      floatx4 tmp = *(const floatx4*)(xrow + k0 + soff + i);
      if (uprow) {
        floatx4 u = *(const floatx4*)(uprow + k0 + soff + i);
        if (statsP) {
#pragma unroll
          for (int j = 0; j < 4; ++j) {
            const int c = k0 + soff + i + j;
            u[j] = scU[c] * u[j] + offU[c];
          }
        }
        tmp += u;
      }
      xv[i] = tmp[0] * scale; xv[i + 1] = tmp[1] * scale;
      xv[i + 2] = tmp[2] * scale; xv[i + 3] = tmp[3] * scale;
    }
    bf16x8 wv[3][2];
#pragma unroll
    for (int s = 0; s < 3; ++s) {
      const bf16* ws = wsrc[s] + (size_t)srow * 128 + k0 + soff;
      wv[s][0] = *(const bf16x8*)ws;
      wv[s][1] = *(const bf16x8*)(ws + 8);
    }
    bf16x8 vh[2], vm[2], vl[2];
#pragma unroll
    for (int i = 0; i < 16; ++i) {
      float v = xv[i];
      bf16 h = (bf16)v; float r1 = v - (float)h;
      bf16 m = (bf16)r1; float r2 = r1 - (float)m;
      vh[i >> 3][i & 7] = h; vm[i >> 3][i & 7] = m; vl[i >> 3][i & 7] = (bf16)r2;
    }
    __syncthreads();
    *(bf16x8*)&Xs[0][sbase] = vh[0]; *(bf16x8*)&Xs[0][sbase + 8] = vh[1];
    *(bf16x8*)&Xs[1][sbase] = vm[0]; *(bf16x8*)&Xs[1][sbase + 8] = vm[1];
    *(bf16x8*)&Xs[2][sbase] = vl[0]; *(bf16x8*)&Xs[2][sbase + 8] = vl[1];
#pragma unroll
    for (int s = 0; s < 3; ++s) {
      *(bf16x8*)&Ws[s][sbase] = wv[s][0];
      *(bf16x8*)&Ws[s][sbase + 8] = wv[s][1];
    }
    __syncthreads();

    bf16x8 af[3][4], bfg[3][4];
#pragma unroll
    for (int s = 0; s < 3; ++s) {
#pragma unroll
      for (int mi = 0; mi < 4; ++mi)
        af[s][mi] = *(const bf16x8*)&Xs[s][(wr * 64 + mi * 16 + lr) * 32 + q * 8];
#pragma unroll
      for (int ni = 0; ni < 4; ++ni)
        bfg[s][ni] = *(const bf16x8*)&Ws[s][(wc * 64 + ni * 16 + lr) * 32 + q * 8];
    }
    constexpr int NT = FULL ? 6 : 3;
    constexpr int sa[6] = {0, 0, 1, 1, 0, 2};
    constexpr int sb[6] = {0, 1, 0, 1, 2, 0};
#pragma unroll
    for (int p = 0; p < NT; ++p)
#pragma unroll
      for (int mi = 0; mi < 4; ++mi)
#pragma unroll
        for (int ni = 0; ni < 4; ++ni)
          acc[mi][ni] = __builtin_amdgcn_mfma_f32_16x16x32_bf16(
              af[sa[p]][mi], bfg[sb[p]][ni], acc[mi][ni], 0, 0, 0);
  }

#pragma unroll
  for (int mi = 0; mi < 4; ++mi) {
    const int rowb = r0 + wr * 64 + mi * 16 + q * 4;
    float dnr[4];
#pragma unroll
    for (int r = 0; r < 4; ++r) dnr[r] = dnv[rowb + r];
#pragma unroll
    for (int ni = 0; ni < 4; ++ni) {
      const int col = wc * 64 + ni * 16 + lr;
      bf16x4 h4, m4, l4;
#pragma unroll
      for (int r = 0; r < 4; ++r) {
        float v = dnr[r] * acc[mi][ni][r];
        Z[(size_t)(rowb + r) * 128 + col] = v;
        Agg[(size_t)(rowb + r) * 128 + col] = 0.0f;
        bf16 h = (bf16)v; float r1 = v - (float)h;
        bf16 m = (bf16)r1; float r2 = r1 - (float)m;
        h4[r] = h; m4[r] = m; l4[r] = (bf16)r2;
      }
      if (Zht) {
        *(bf16x4*)&Zht[(size_t)col * ldz + rowb] = h4;
        *(bf16x4*)&Zmt[(size_t)col * ldz + rowb] = m4;
        if (FULL) *(bf16x4*)&Zlt[(size_t)col * ldz + rowb] = l4;
      }
    }
  }
}

// ---------------------------------------------------------------------------
// Fused prep: blocks [0,4096): adj->bf16 row + ordered neighbor list + deg
// + dn (=1/sqrt(deg+2); deg == row sum since entries are {0,1});
// [4096,4544) conv_w 3-way split; block 4544 pool_w inverse norms.
// ---------------------------------------------------------------------------
__global__ void prep_all(const float* __restrict__ adj, bf16* __restrict__ ah,
                         float* __restrict__ dn, int n,
                         unsigned short* __restrict__ nbr, int* __restrict__ deg,
                         const float* __restrict__ W, bf16* __restrict__ Wh,
                         bf16* __restrict__ Wm, bf16* __restrict__ Wl,
                         const float* __restrict__ pw, float* __restrict__ invp) {
  const int bid = blockIdx.x;
  const int t = threadIdx.x;
  __shared__ int wsum4[4];
  __shared__ float red[128];
  if (bid < 4096) {
    const int r = bid;
    const float* arow = adj + (size_t)r * n;
    bf16* orow = ah + (size_t)r * n;
    const int base = t * 16;
    floatx4 buf[4];
#pragma unroll
    for (int i = 0; i < 4; ++i) buf[i] = *(const floatx4*)(arow + base + i * 4);
    int cnt = 0;
#pragma unroll
    for (int i = 0; i < 4; ++i) {
      bf16x4 o;
#pragma unroll
      for (int e = 0; e < 4; ++e) {
        float x = (base + i * 4 + e == r) ? 0.0f : buf[i][e];
        buf[i][e] = x;
        cnt += (x != 0.0f) ? 1 : 0;
        o[e] = (bf16)x;
      }
      *(bf16x4*)&orow[base + i * 4] = o;
    }
    const int lane = t & 63, wid = t >> 6;
    int vc = cnt;
#pragma unroll
    for (int off = 1; off < 64; off <<= 1) {
      int u = __shfl_up(vc, off, 64);
      if (lane >= off) vc += u;
    }
    if (lane == 63) wsum4[wid] = vc;
    __syncthreads();
    int add = 0;
    for (int wi = 0; wi < wid; ++wi) add += wsum4[wi];
    int o = vc + add - cnt;       // exclusive prefix (ascending-order slot)
    const int total = wsum4[0] + wsum4[1] + wsum4[2] + wsum4[3];
    unsigned short* rn = nbr + (size_t)r * 256;
#pragma unroll
    for (int i = 0; i < 4; ++i)
#pragma unroll
      for (int e = 0; e < 4; ++e)
        if (buf[i][e] != 0.0f) {
          if (o < 256) rn[o] = (unsigned short)(base + i * 4 + e);
          ++o;
        }
    if (t == 0) {
      deg[r] = total < 256 ? total : 256;
      dn[r] = 1.0f / sqrtf((float)total + 2.0f);
    }
  } else if (bid < 4544) {
    int idx = (bid - 4096) * 256 + t;
    int l = idx >> 14, rem = idx & 16383, c = rem >> 7, k = rem & 127;
    float v = W[(l << 14) + (k << 7) + c];
    bf16 h = (bf16)v; float r1 = v - (float)h;
    bf16 m = (bf16)r1; float r2 = r1 - (float)m;
    Wh[idx] = h; Wm[idx] = m; Wl[idx] = (bf16)r2;
  } else {
    if (t < 128) {
      for (int l = 0; l < 3; ++l) {
        float v = pw[l * 128 + t];
        red[t] = v * v; __syncthreads();
        for (int off = 64; off; off >>= 1) {
          if (t < off) red[t] += red[t + off];
          __syncthreads();
        }
        if (t == 0) invp[l] = 1.0f / sqrtf(red[0]);
        __syncthreads();
      }
    }
  }
}

__global__ void dn_rows_bf(const bf16* __restrict__ A, int lda, float* __restrict__ dn,
                           int n) {
  int r = blockIdx.x, t = threadIdx.x;
  const bf16* row = A + (size_t)r * lda;
  float sum = 0.f;
  for (int c4 = t * 4; c4 < n; c4 += 1024) {
    bf16x4 v = *(const bf16x4*)&row[c4];
#pragma unroll
    for (int e = 0; e < 4; ++e) sum += (float)v[e];
  }
  __shared__ float red[256];
  red[t] = sum; __syncthreads();
  for (int off = 128; off; off >>= 1) {
    if (t < off) red[t] += red[t + off];
    __syncthreads();
  }
  if (t == 0) dn[r] = 1.0f / sqrtf(red[0] + 2.0f);
}

__global__ void dn_rows(const float* __restrict__ A, int lda, float* __restrict__ dn,
                        int n) {
  int r = blockIdx.x, t = threadIdx.x;
  const float* row = A + (size_t)r * lda;
  float sum = 0.f;
  for (int c = t; c < n; c += 256)
    if (c != r) sum += row[c];
  __shared__ float red[256];
  red[t] = sum; __syncthreads();
  for (int off = 128; off; off >>= 1) {
    if (t < off) red[t] += red[t + off];
    __syncthreads();
  }
  if (t == 0) dn[r] = 1.0f / sqrtf(red[0] + 2.0f);
}

// ---------------------------------------------------------------------------
// Fused top-k select: radix k-th largest (snapshot-fixed) + deterministic
// compaction (+inverse perm) in one single-block kernel.
// ---------------------------------------------------------------------------
__device__ inline unsigned f2u(float f) {
  unsigned u = __float_as_uint(f);
  return (u & 0x80000000u) ? ~u : (u | 0x80000000u);
}
__global__ __launch_bounds__(1024) void select_kernel(
    const float* __restrict__ s, int n, int k,
    int* __restrict__ perm, float* __restrict__ vals, int* __restrict__ inv)
{
  __shared__ int hist[256];
  __shared__ unsigned sh_prefix;
  __shared__ int sh_krem;
  __shared__ float sh_thr;
  __shared__ int wsum[16];
  __shared__ int wgs[16], wes[16];
  const int t = threadIdx.x;
  const int lane = t & 63;
  const int wid = t >> 6;
  if (t == 0) { sh_prefix = 0; sh_krem = k; }

  for (int round = 0; round < 4; ++round) {
    const int shift = 24 - 8 * round;
    if (t < 256) hist[t] = 0;
    __syncthreads();
    const unsigned pref = sh_prefix;
    const int krem = sh_krem;
    for (int i = t; i < n; i += 1024) {
      unsigned u = f2u(s[i]);
      if (round == 0 || (u >> (shift + 8)) == pref)
        atomicAdd(&hist[(u >> shift) & 255], 1);
    }
    __syncthreads();
    int v = 0, own = 0;
    if (t < 256) {
      own = hist[255 - t];
      v = own;
#pragma unroll
      for (int off = 1; off < 64; off <<= 1) {
        int u = __shfl_up(v, off, 64);
        if (lane >= off) v += u;
      }
      if (lane == 63) wsum[wid] = v;
    }
    __syncthreads();
    if (t < 256) {
      int add = 0;
      for (int wi = 0; wi < wid; ++wi) add += wsum[wi];
      v += add;
      const int prev = v - own;
      if (v >= krem && prev < krem) {
        sh_prefix = (pref << 8) | (unsigned)(255 - t);
        sh_krem = krem - prev;
      }
    }
    __syncthreads();
  }
  if (t == 0) {
    unsigned u = sh_prefix;
    sh_thr = (u & 0x80000000u) ? __uint_as_float(u & 0x7fffffffu)
                               : __uint_as_float(~u);
  }
  for (int i = t; i < n; i += 1024) inv[i] = -1;
  __syncthreads();

  const float thr = sh_thr;
  const int chunk = n >> 10;
  const int beg = t * chunk;
  int g = 0, e = 0;
  for (int i = 0; i < chunk; ++i) {
    float v = s[beg + i];
    g += (v > thr); e += (v == thr);
  }
  int vg = g, ve = e;
#pragma unroll
  for (int off = 1; off < 64; off <<= 1) {
    int ug = __shfl_up(vg, off, 64);
    int ue = __shfl_up(ve, off, 64);
    if (lane >= off) { vg += ug; ve += ue; }
  }
  if (lane == 63) { wgs[wid] = vg; wes[wid] = ve; }
  __syncthreads();
  int ag = 0, ae = 0;
  for (int wi = 0; wi < wid; ++wi) { ag += wgs[wi]; ae += wes[wi]; }
  int total_gt = 0;
#pragma unroll
  for (int wi = 0; wi < 16; ++wi) total_gt += wgs[wi];
  int pg = vg + ag - g;
  int pe = ve + ae - e;
  const int need = k - total_gt;
  for (int i = 0; i < chunk; ++i) {
    float v = s[beg + i];
    if (v > thr) {
      if (pg < k) { perm[pg] = beg + i; vals[pg] = v; inv[beg + i] = pg; }
      ++pg;
    } else if (v == thr) {
      if (pe < need && total_gt + pe < k) {
        perm[total_gt + pe] = beg + i; vals[total_gt + pe] = v;
        inv[beg + i] = total_gt + pe;
      }
      ++pe;
    }
  }
}

// Gather R=(A+I)[perm] as int8 (exact small-int A entries), diag forced to 1.
__global__ void gather_i8(const bf16* __restrict__ src, int lda,
                          const int* __restrict__ perm, char* __restrict__ R, int n) {
  int j = blockIdx.x, t = threadIdx.x;
  int r = perm[j];
  const bf16* s = src + (size_t)r * lda;
  char* o = R + (size_t)j * n;
  for (int c = t * 8; c < n; c += 2048) {
    bf16x8 v = *(const bf16x8*)&s[c];
    cx8 ob;
#pragma unroll
    for (int e = 0; e < 8; ++e)
      ob[e] = (c + e == r) ? (char)1 : (char)(float)v[e];
    *(cx8*)&o[c] = ob;
  }
}

__global__ void gather_f32(const float* __restrict__ src, int lda,
                           const int* __restrict__ perm, bf16* __restrict__ R, int n) {
  int j = blockIdx.x, t = threadIdx.x;
  int r = perm[j];
  const float* s = src + (size_t)r * lda;
  bf16* o = R + (size_t)j * n;
  for (int c4 = t * 4; c4 < n; c4 += 1024) {
    floatx4 v = *(const floatx4*)(s + c4);
    bf16x4 ob;
#pragma unroll
    for (int e = 0; e < 4; ++e)
      ob[e] = (c4 + e == r) ? (bf16)1.0f : (bf16)v[e];
    *(bf16x4*)&o[c4] = ob;
  }
}

// y = dn[r]*(Agg + 2*Z) + bias; relu?; write H to hout; BN col stats.
__global__ void gcn_post(float* __restrict__ acc, const float* __restrict__ Zf,
                         const float* __restrict__ dn, const float* __restrict__ bias,
                         float* __restrict__ stats, int relu,
                         float* __restrict__ hout) {
  int c = threadIdx.x;
  int r0 = blockIdx.x * 16;
  float b = bias[c];
  float s = 0.f, qq = 0.f;
  for (int i = 0; i < 16; ++i) {
    int r = r0 + i;
    float v = dn[r] * (acc[(size_t)r * 128 + c] + 2.0f * Zf[(size_t)r * 128 + c]) + b;
    if (relu) v = fmaxf(v, 0.f);
    hout[(size_t)r * 128 + c] = v;
    s += v; qq += v * v;
  }
  atomicAdd(&stats[c], s);
  atomicAdd(&stats[128 + c], qq);
}

// BN apply (coef recomputed per block) + optional fused pooling score.
__global__ void bn_apply(const float* __restrict__ H, const float* __restrict__ stats,
                         const float* __restrict__ g, const float* __restrict__ b,
                         int n, float* __restrict__ xout,
                         const float* __restrict__ pw, const float* __restrict__ invp,
                         float* __restrict__ scores) {
  int r = blockIdx.x, c = threadIdx.x;
  float m = stats[c] / n;
  float var = stats[128 + c] / n - m * m;
  float sc = g[c] / sqrtf(var + 1e-5f);
  float off = b[c] - m * sc;
  float v = sc * H[(size_t)r * 128 + c] + off;
  xout[(size_t)r * 128 + c] = v;
  if (pw) {
    __shared__ float red[128];
    red[c] = v * pw[c]; __syncthreads();
    for (int o = 64; o; o >>= 1) {
      if (c < o) red[c] += red[c + o];
      __syncthreads();
    }
    if (c == 0) scores[r] = tanhf(red[0] * invp[0]);
  }
}

// ---------------------------------------------------------------------------
extern "C" void kernel_launch(void* const* d_in, const int* in_sizes, int n_in,
                              void* d_out, int out_size, void* d_ws, size_t ws_size,
                              hipStream_t stream) {
  const float* x_in   = (const float*)d_in[0];
  const float* adj    = (const float*)d_in[1];
  const float* conv_w = (const float*)d_in[2];
  const float* conv_b = (const float*)d_in[3];
  const float* pool_w = (const float*)d_in[4];
  const float* bn_g   = (const float*)d_in[5];
  const float* bn_b   = (const float*)d_in[6];
  float* out = (float*)d_out;
  (void)in_sizes; (void)n_in; (void)out_size; (void)ws_size;

  char* p = (char*)d_ws;
  auto alloc = [&](size_t bytes) -> void* {
    void* r = (void*)p;
    p += (bytes + 255) & ~(size_t)255;
    return r;
  };
  bf16*  Ah0bf = (bf16*)alloc(4096ull * 4096 * 2);
  bf16*  A1bf  = (bf16*)alloc(2048ull * 2048 * 2);
  float* A2f   = (float*)alloc(1024ull * 1024 * 4);
  float* A3f   = (float*)alloc(512ull * 512 * 4);
  char*  Rbuf  = (char*)alloc(2048ull * 4096 * 2);  // i8 (pools 0/1) or bf16 (pool 2)
  void*  Cs    = alloc(40ull << 20);   // p0: 4z i16 17.8MB / p1: 8z i32 18.9MB / p2: 8z f32
  float* Z     = (float*)alloc(4096ull * 128 * 4);
  bf16*  Zht   = (bf16*)alloc(128ull * 4096 * 2);
  bf16*  Zmt   = (bf16*)alloc(128ull * 4096 * 2);
  bf16*  Zlt   = (bf16*)alloc(128ull * 4096 * 2);
  float* Agg   = (float*)alloc(4096ull * 128 * 4);
  float* res0  = (float*)alloc(4096ull * 128 * 4);
  float* res1  = (float*)alloc(2048ull * 128 * 4);
  float* res2  = (float*)alloc(1024ull * 128 * 4);
  float* xb0   = (float*)alloc(512ull * 128 * 4);
  float* xb1   = (float*)alloc(1024ull * 128 * 4);
  float* xb2   = (float*)alloc(2048ull * 128 * 4);
  bf16*  Wh    = (bf16*)alloc(7ull * 16384 * 2);
  bf16*  Wm    = (bf16*)alloc(7ull * 16384 * 2);
  bf16*  Wl    = (bf16*)alloc(7ull * 16384 * 2);
  unsigned short* nbr = (unsigned short*)alloc(4096ull * 256 * 2 + 1024);
  int*   deg   = (int*)alloc(4096 * 4);
  float* scores = (float*)alloc(4096 * 4);
  int*   perm0 = (int*)alloc(2048 * 4);
  int*   perm1 = (int*)alloc(1024 * 4);
  int*   perm2 = (int*)alloc(512 * 4);
  int*   inv0  = (int*)alloc(4096 * 4);
  int*   inv1  = (int*)alloc(2048 * 4);
  int*   inv2  = (int*)alloc(1024 * 4);
  float* vals0 = (float*)alloc(2048 * 4);
  float* vals1 = (float*)alloc(1024 * 4);
  float* vals2 = (float*)alloc(512 * 4);
  float* dn0   = (float*)alloc(4096 * 4);
  float* dn1   = (float*)alloc(2048 * 4);
  float* dn2   = (float*)alloc(1024 * 4);
  float* dn3   = (float*)alloc(512 * 4);
  float* invp  = (float*)alloc(256);
  float* stats = (float*)alloc(7ull * 256 * 4);   // per-layer BN stats

  auto gcn = [&](int nr, const bf16* Abf, const float* Af32,
                 const unsigned short* nbrp, const float* dnv,
                 int layer, const float* xsrc, const int* perm, const float* vals,
                 const float* up, const int* inv, float* xout, int relu, int aTwo,
                 const float* pw, const float* ip, int full,
                 const float* statsP, const float* gP, const float* bPv, float nP,
                 int doBn) {
    float* st = stats + layer * 256;
    bf16* zht = nbrp ? nullptr : Zht;
    bf16* zmt = nbrp ? nullptr : Zmt;
    bf16* zlt = nbrp ? nullptr : Zlt;
    if (full)
      xw_split<1><<<nr / 128, 256, 0, stream>>>(
          xsrc, perm, vals, up, inv, statsP, gP, bPv, nP,
          Wh + layer * 16384, Wm + layer * 16384, Wl + layer * 16384, dnv,
          Z, zht, zmt, zlt, nr, Agg, st);
    else
      xw_split<0><<<nr / 128, 256, 0, stream>>>(
          xsrc, perm, vals, up, inv, statsP, gP, bPv, nP,
          Wh + layer * 16384, Wm + layer * 16384, Wl + layer * 16384, dnv,
          Z, zht, zmt, zlt, nr, Agg, st);
    if (nbrp) {
      agg_sparse<<<nr / 4, 256, 0, stream>>>(nbrp, deg, Z, Agg);
    } else if (Abf) {
      if (full)
        agg_bf<3><<<dim3(nr / 64, 8), 256, 0, stream>>>(
            Abf, nr, Zht, Zmt, Zlt, nr, Agg, nr / 256);
      else
        agg_bf<2><<<dim3(nr / 64, 8), 256, 0, stream>>>(
            Abf, nr, Zht, Zmt, Zlt, nr, Agg, nr / 256);
    } else {
      if (full)
        agg_split<3><<<dim3(nr / 64, 8), 256, 0, stream>>>(
            Af32, nr, Zht, Zmt, Zlt, nr, Agg, nr / 256, aTwo);
      else
        agg_split<2><<<dim3(nr / 64, 8), 256, 0, stream>>>(
            Af32, nr, Zht, Zmt, Zlt, nr, Agg, nr / 256, aTwo);
    }
    gcn_post<<<nr / 16, 128, 0, stream>>>(Agg, Z, dnv, conv_b + layer * 128, st, relu,
                                          doBn ? Agg : xout);
    if (doBn)
      bn_apply<<<nr, 128, 0, stream>>>(Agg, st, bn_g + layer * 128, bn_b + layer * 128,
                                       nr, xout, pw, ip, scores);
  };

  // Pool: select -> gather R=(A+I)[perm] -> 128^2 R R^T -> sym_post -> dn.
  auto pool = [&](int n, const bf16* srcBf, const float* srcF32,
                  bf16* outBf, float* outF32, float* dnNew,
                  int* perm, float* vals, int* inv, int splitZ, int mode) {
    int k = n / 2, G = k / 128, pairs = G * (G + 1) / 2;
    select_kernel<<<1, 1024, 0, stream>>>(scores, n, k, perm, vals, inv);
    if (mode <= 1) {
      gather_i8<<<k, 256, 0, stream>>>(srcBf, n, perm, Rbuf, n);
      gemm_sym_i8<<<dim3(pairs, splitZ), 256, 0, stream>>>(
          Rbuf, mode == 0 ? (short*)Cs : nullptr, mode == 0 ? nullptr : (int*)Cs,
          n, n / (splitZ * 64), G, pairs);
      sym_post_i<<<dim3(pairs, 16), 256, 0, stream>>>(
          mode == 0 ? (const short*)Cs : nullptr, mode == 0 ? nullptr : (const int*)Cs,
          outBf, outF32, k, G, pairs, splitZ);
    } else {
      gather_f32<<<k, 256, 0, stream>>>(srcF32, n, perm, (bf16*)Rbuf, n);
      gemm_sym<<<dim3(pairs, splitZ), 256, 0, stream>>>(
          (const bf16*)Rbuf, (float*)Cs, n, n / (splitZ * 32), G, pairs);
      sym_post<<<dim3(pairs, 16), 256, 0, stream>>>(
          (const float*)Cs, outF32, k, G, pairs, splitZ);
    }
    if (outBf) dn_rows_bf<<<k, 256, 0, stream>>>(outBf, k, dnNew, k);
    else       dn_rows<<<k, 256, 0, stream>>>(outF32, k, dnNew, k);
  };

  // ---- prep (one launch; also builds ordered adjacency for layer 6) ----
  prep_all<<<4545, 256, 0, stream>>>(adj, Ah0bf, dn0, 4096, nbr, deg,
                                     conv_w, Wh, Wm, Wl, pool_w, invp);

  // ---- down ---- (identical numerics to the verified round-7 config)
  gcn(4096, Ah0bf, nullptr, nullptr, dn0, 0, x_in, nullptr, nullptr, nullptr, nullptr,
      res0, 1, 0, pool_w + 0, invp + 0, 1, nullptr, nullptr, nullptr, 1.0f, 1);
  pool(4096, Ah0bf, nullptr, A1bf, nullptr, dn1, perm0, vals0, inv0, 4, 0);
  gcn(2048, A1bf, nullptr, nullptr, dn1, 1, res0, perm0, vals0, nullptr, nullptr,
      res1, 1, 0, pool_w + 128, invp + 1, 1, nullptr, nullptr, nullptr, 1.0f, 1);
  pool(2048, A1bf, nullptr, nullptr, A2f, dn2, perm1, vals1, inv1, 8, 1);
  gcn(1024, nullptr, A2f, nullptr, dn2, 2, res1, perm1, vals1, nullptr, nullptr,
      res2, 1, 1, pool_w + 256, invp + 2, 1, nullptr, nullptr, nullptr, 1.0f, 1);
  pool(1024, nullptr, A2f, nullptr, A3f, dn3, perm2, vals2, inv2, 8, 2);
  gcn(512, nullptr, A3f, nullptr, dn3, 3, res2, perm2, vals2, nullptr, nullptr,
      xb0, 1, 1, nullptr, nullptr, 0, nullptr, nullptr, nullptr, 1.0f, 0);

  // ---- up ---- (layer 6: post-selection output path -> sparse agg)
  gcn(1024, nullptr, A2f, nullptr, dn2, 4, res2, nullptr, nullptr, xb0, inv2,
      xb1, 1, 1, nullptr, nullptr, 0,
      stats + 3 * 256, bn_g + 3 * 128, bn_b + 3 * 128, 512.0f, 0);
  gcn(2048, A1bf, nullptr, nullptr, dn1, 5, res1, nullptr, nullptr, xb1, inv1,
      xb2, 1, 0, nullptr, nullptr, 0,
      stats + 4 * 256, bn_g + 4 * 128, bn_b + 4 * 128, 1024.0f, 0);
  gcn(4096, nullptr, nullptr, nbr, dn0, 6, res0, nullptr, nullptr, xb2, inv0,
      out, 0, 0, nullptr, nullptr, 0,
      stats + 5 * 256, bn_g + 5 * 128, bn_b + 5 * 128, 2048.0f, 1);
}